// Round 1
// 545.121 us; speedup vs baseline: 1.3645x; 1.3645x over previous
//
#include <hip/hip_runtime.h>
#include <hip/hip_bf16.h>

#define N_NODES 50000
#define K_NBR   16
#define DIN     128
#define DOUT    64
#define NPB     64   // nodes per block in the linear kernels
#define NPW     16   // nodes per wave  (4 waves/block)

typedef __hip_bfloat16 bf16;

__device__ __forceinline__ float b2f(bf16 v) { return __bfloat162float(v); }
__device__ __forceinline__ float sigmoidf_(float x) { return 1.0f / (1.0f + __expf(-x)); }

template <typename T> __device__ __forceinline__ float ld(const T* p, size_t i);
template <> __device__ __forceinline__ float ld<float>(const float* p, size_t i) { return p[i]; }
template <> __device__ __forceinline__ float ld<bf16>(const bf16* p, size_t i)   { return b2f(p[i]); }

template <typename T> __device__ __forceinline__ void st(T* p, size_t i, float v);
template <> __device__ __forceinline__ void st<float>(float* p, size_t i, float v) { p[i] = v; }
template <> __device__ __forceinline__ void st<bf16>(bf16* p, size_t i, float v)   { p[i] = __float2bfloat16(v); }

// ---------------------------------------------------------------------------
// Dtype detector: view input as 16-bit words. For a true-bf16 array, the even
// (low-half-of-dword) elements are sane bf16 gaussians (exp in [112,142]).
// For an f32 array, low halves are mantissa garbage (~12% in range).
// flag: 1 = float32 data, 0 = bf16 data.
// ---------------------------------------------------------------------------
__global__ void detect_kernel(const unsigned short* __restrict__ x, int* __restrict__ flag)
{
    __shared__ int cnt;
    if (threadIdx.x == 0) cnt = 0;
    __syncthreads();
    int c = 0;
#pragma unroll
    for (int i = 0; i < 16; ++i) {
        unsigned short w = x[(size_t)(threadIdx.x * 16 + i) * 2];  // low half-word
        int e = (w >> 7) & 0xFF;
        c += (e >= 112 && e <= 142) ? 1 : 0;
    }
    atomicAdd(&cnt, c);
    __syncthreads();
    if (threadIdx.x == 0) *flag = (cnt >= 2048) ? 0 : 1;
}

// ---------------------------------------------------------------------------
// Node-blocked dual linear: xn = x @ We (f32), o[:, :64] = sigmoid(x @ Ws).
// 64 nodes per block staged in LDS (transposed, pad 68 keeps float4 rows
// 16B-aligned and staging writes at 8-way conflict only). Each wave owns 16
// nodes x 64 dims; per-i weight loads are amortized over 16 nodes (16x less
// L1 traffic than the 1-node-per-wave version, which was L1-bound at 20%
// VALUBusy).
// ---------------------------------------------------------------------------
template <typename TX, typename TW, typename TO>
__device__ __forceinline__ void lin_body(
    const TX* __restrict__ x, const TW* __restrict__ We, const TW* __restrict__ Ws,
    float* __restrict__ xn, TO* __restrict__ o)
{
    __shared__ __align__(16) float xs[DIN][NPB + 4];   // 34.8 KB -> 4 blocks/CU
    const int warp = threadIdx.x >> 6;
    const int lane = threadIdx.x & 63;
    const int nbase = blockIdx.x * NPB;

    // Stage 64 node rows, coalesced global reads (consecutive lanes ->
    // consecutive i within a row). Tail block clamps to a valid row.
#pragma unroll 8
    for (int r = 0; r < 32; ++r) {
        int e  = threadIdx.x + 256 * r;   // 0..8191
        int nn = e >> 7;                  // 0..63
        int i  = e & 127;
        int n  = nbase + nn;
        if (n >= N_NODES) n = N_NODES - 1;
        xs[i][nn] = ld(x, (size_t)n * DIN + i);
    }
    __syncthreads();

    const int d  = lane;        // output dim
    const int nw = warp * NPW;  // this wave's first local node
    float accE[NPW], accS[NPW];
#pragma unroll
    for (int j = 0; j < NPW; ++j) { accE[j] = 0.f; accS[j] = 0.f; }

#pragma unroll 2
    for (int i = 0; i < DIN; ++i) {
        float we = ld(We, (size_t)i * DOUT + d);   // L1-resident, coalesced
        float ws = ld(Ws, (size_t)i * DOUT + d);
        const float4* __restrict__ xp = (const float4*)&xs[i][nw];  // broadcast reads
#pragma unroll
        for (int q = 0; q < NPW / 4; ++q) {
            float4 xv = xp[q];
            accE[4*q+0] += xv.x * we; accS[4*q+0] += xv.x * ws;
            accE[4*q+1] += xv.y * we; accS[4*q+1] += xv.y * ws;
            accE[4*q+2] += xv.z * we; accS[4*q+2] += xv.z * ws;
            accE[4*q+3] += xv.w * we; accS[4*q+3] += xv.w * ws;
        }
    }

#pragma unroll
    for (int j = 0; j < NPW; ++j) {
        int n = nbase + nw + j;
        if (n < N_NODES) {
            xn[(size_t)n * DOUT + d] = accE[j];                    // coalesced 256B
            st(o, (size_t)n * DIN + d, sigmoidf_(accS[j]));
        }
    }
}

__global__ __launch_bounds__(256) void lin1_kernel(
    const void* __restrict__ x1, const void* __restrict__ x2,
    const void* __restrict__ We, const void* __restrict__ Ws,
    float* __restrict__ xn1, float* __restrict__ xn2,
    bf16* __restrict__ h1, bf16* __restrict__ h2,
    const int* __restrict__ flag)
{
    const int g = blockIdx.y;
    const void* x  = g ? x2 : x1;
    float*      xn = g ? xn2 : xn1;
    bf16*       h  = g ? h2 : h1;
    if (*flag) lin_body<float, float, bf16>((const float*)x, (const float*)We, (const float*)Ws, xn, h);
    else       lin_body<bf16,  bf16,  bf16>((const bf16*)x,  (const bf16*)We,  (const bf16*)Ws,  xn, h);
}

// ---------------------------------------------------------------------------
// Pass B: aggr = (1/K) sum_k xn[nbr[n,k]] (f32), h[:, 64:] = sigmoid(aggr)
// ---------------------------------------------------------------------------
__global__ __launch_bounds__(256) void aggr1_kernel(
    const int* __restrict__ nbr1, const int* __restrict__ nbr2,
    const float* __restrict__ xn1, const float* __restrict__ xn2,
    float* __restrict__ ag1, float* __restrict__ ag2,
    bf16* __restrict__ h1, bf16* __restrict__ h2)
{
    const int g = blockIdx.y;
    const int*   __restrict__ nbr = g ? nbr2 : nbr1;
    const float* __restrict__ xn  = g ? xn2 : xn1;
    float*       __restrict__ ag  = g ? ag2 : ag1;
    bf16*        __restrict__ h   = g ? h2 : h1;

    const int warp = threadIdx.x >> 6;
    const int lane = threadIdx.x & 63;
    const int n = blockIdx.x * 4 + warp;

    int idx_l = nbr[n * K_NBR + (lane & 15)];
    float acc = 0.f;
#pragma unroll
    for (int k = 0; k < K_NBR; ++k) {
        int idx = __shfl(idx_l, k, 64);
        acc += xn[(size_t)idx * DOUT + lane];
    }
    acc *= (1.0f / K_NBR);
    ag[(size_t)n * DOUT + lane] = acc;
    h[(size_t)n * DIN + DOUT + lane] = __float2bfloat16(sigmoidf_(acc));
}

// ---------------------------------------------------------------------------
// Pass C: fused self-attn + cross-attn -> norm1/norm2 [N,K] (f32)
// One 256-thread block per node. K x K pairwise distances in LDS.
// ---------------------------------------------------------------------------
template <typename T>
__device__ __forceinline__ void attn_body(
    const int* __restrict__ nbr1, const int* __restrict__ nbr2,
    const float* __restrict__ ag1, const float* __restrict__ ag2,
    const T* __restrict__ w_att,
    float* __restrict__ norm1, float* __restrict__ norm2)
{
    const int n = blockIdx.x;
    const int t = threadIdx.x;

    __shared__ float a1[K_NBR][DOUT + 1];
    __shared__ float a2[K_NBR][DOUT + 1];
    __shared__ float own1[DOUT], own2[DOUT], wlo[DOUT], whi[DOUT];
    __shared__ float sim[K_NBR][K_NBR + 1];
    __shared__ float rs[K_NBR], cs[K_NBR], e1[K_NBR], e2[K_NBR];
    __shared__ float red[5]; // total, si1, si2, se1, se2

#pragma unroll
    for (int r = 0; r < 4; ++r) {
        int e = t + 256 * r;
        int k = e >> 6, d = e & 63;
        a1[k][d] = ag1[(size_t)nbr1[n * K_NBR + k] * DOUT + d];
        a2[k][d] = ag2[(size_t)nbr2[n * K_NBR + k] * DOUT + d];
    }
    if (t < 64)        own1[t]       = ag1[(size_t)n * DOUT + t];
    else if (t < 128)  own2[t - 64]  = ag2[(size_t)n * DOUT + (t - 64)];
    else if (t < 192)  wlo[t - 128]  = ld(w_att, t - 128);
    else               whi[t - 192]  = ld(w_att, 64 + (t - 192));
    __syncthreads();

    {
        int k = t >> 4, l = t & 15;
        float d2 = 0.f;
#pragma unroll 8
        for (int d = 0; d < DOUT; ++d) {
            float df = a1[k][d] - a2[l][d];
            d2 += df * df;
        }
        sim[k][l] = __expf(-sqrtf(fmaxf(d2, 1e-12f)));
    }
    __syncthreads();

    if (t < 16) {                 // row sums (over l)
        float s = 0.f;
        for (int l = 0; l < 16; ++l) s += sim[t][l];
        rs[t] = s;
    } else if (t < 32) {          // col sums (over k)
        int l = t - 16; float s = 0.f;
        for (int k = 0; k < 16; ++k) s += sim[k][l];
        cs[l] = s;
    } else if (t < 48) {          // sj1[k] = a1_k . w_hi
        int k = t - 32; float s = 0.f;
        for (int d = 0; d < 64; ++d) s += a1[k][d] * whi[d];
        e1[k] = s;
    } else if (t < 64) {          // sj2[k]
        int k = t - 48; float s = 0.f;
        for (int d = 0; d < 64; ++d) s += a2[k][d] * whi[d];
        e2[k] = s;
    } else if (t == 64) {         // si1 = own1 . w_lo
        float s = 0.f;
        for (int d = 0; d < 64; ++d) s += own1[d] * wlo[d];
        red[1] = s;
    } else if (t == 65) {         // si2
        float s = 0.f;
        for (int d = 0; d < 64; ++d) s += own2[d] * wlo[d];
        red[2] = s;
    }
    __syncthreads();

    if (t < 16) {
        float v = red[1] + e1[t];
        v = v > 0.f ? v : 0.01f * v;
        e1[t] = __expf(v);
    } else if (t < 32) {
        int k = t - 16;
        float v = red[2] + e2[k];
        v = v > 0.f ? v : 0.01f * v;
        e2[k] = __expf(v);
    }
    __syncthreads();

    if (t == 0)      { float s = 0.f; for (int k = 0; k < 16; ++k) s += rs[k]; red[0] = s; }
    else if (t == 1) { float s = 0.f; for (int k = 0; k < 16; ++k) s += e1[k]; red[3] = s; }
    else if (t == 2) { float s = 0.f; for (int k = 0; k < 16; ++k) s += e2[k]; red[4] = s; }
    __syncthreads();

    if (t < 16) {
        norm1[(size_t)n * K_NBR + t] = (rs[t] / red[0]) * (e1[t] / red[3]);
    } else if (t < 32) {
        int l = t - 16;
        norm2[(size_t)n * K_NBR + l] = (cs[l] / red[0]) * (e2[l] / red[4]);
    }
}

__global__ __launch_bounds__(256) void attn_kernel(
    const int* __restrict__ nbr1, const int* __restrict__ nbr2,
    const float* __restrict__ ag1, const float* __restrict__ ag2,
    const void* __restrict__ w_att,
    float* __restrict__ norm1, float* __restrict__ norm2,
    const int* __restrict__ flag)
{
    if (*flag) attn_body<float>(nbr1, nbr2, ag1, ag2, (const float*)w_att, norm1, norm2);
    else       attn_body<bf16>(nbr1, nbr2, ag1, ag2, (const bf16*)w_att,  norm1, norm2);
}

// ---------------------------------------------------------------------------
// Pass D: he = h @ W_e2 (f32), out[:, :64] = sigmoid(h @ W_s2)
// Same node-blocked structure as lin1 (h is always bf16).
// ---------------------------------------------------------------------------
__global__ __launch_bounds__(256) void lin2_kernel(
    const bf16* __restrict__ h1, const bf16* __restrict__ h2,
    const void* __restrict__ We2, const void* __restrict__ Ws2,
    float* __restrict__ he1, float* __restrict__ he2,
    void* __restrict__ out, const int* __restrict__ flag)
{
    const int g = blockIdx.y;
    const bf16* h  = g ? h2 : h1;
    float*      he = g ? he2 : he1;
    if (*flag) lin_body<bf16, float, float>(h, (const float*)We2, (const float*)Ws2, he,
                                            (float*)out + (size_t)g * N_NODES * DIN);
    else       lin_body<bf16, bf16,  bf16 >(h, (const bf16*)We2,  (const bf16*)Ws2,  he,
                                            (bf16*)out + (size_t)g * N_NODES * DIN);
}

// ---------------------------------------------------------------------------
// Pass E: out[:, 64:] = sigmoid(sum_k norm[n,k] * he[nbr[n,k]])
// ---------------------------------------------------------------------------
template <typename T>
__device__ __forceinline__ void aggr2_body(
    const int* __restrict__ nbr, const float* __restrict__ he,
    const float* __restrict__ nm, T* __restrict__ o)
{
    const int warp = threadIdx.x >> 6;
    const int lane = threadIdx.x & 63;
    const int n = blockIdx.x * 4 + warp;

    int   idx_l = nbr[n * K_NBR + (lane & 15)];
    float w_l   = nm[n * K_NBR + (lane & 15)];
    float acc = 0.f;
#pragma unroll
    for (int k = 0; k < K_NBR; ++k) {
        int   idx = __shfl(idx_l, k, 64);
        float w   = __shfl(w_l, k, 64);
        acc += w * he[(size_t)idx * DOUT + lane];
    }
    st(o, (size_t)n * DIN + DOUT + lane, sigmoidf_(acc));
}

__global__ __launch_bounds__(256) void aggr2_kernel(
    const int* __restrict__ nbr1, const int* __restrict__ nbr2,
    const float* __restrict__ he1, const float* __restrict__ he2,
    const float* __restrict__ nm1, const float* __restrict__ nm2,
    void* __restrict__ out, const int* __restrict__ flag)
{
    const int g = blockIdx.y;
    const int*   nbr = g ? nbr2 : nbr1;
    const float* he  = g ? he2 : he1;
    const float* nm  = g ? nm2 : nm1;
    if (*flag) aggr2_body<float>(nbr, he, nm, (float*)out + (size_t)g * N_NODES * DIN);
    else       aggr2_body<bf16>(nbr, he, nm, (bf16*)out + (size_t)g * N_NODES * DIN);
}

// ---------------------------------------------------------------------------
extern "C" void kernel_launch(void* const* d_in, const int* in_sizes, int n_in,
                              void* d_out, int out_size, void* d_ws, size_t ws_size,
                              hipStream_t stream)
{
    const void* x1   = d_in[0];
    const void* x2   = d_in[1];
    const int*  nbr1 = (const int*)d_in[2];
    const int*  nbr2 = (const int*)d_in[3];
    const void* We1  = d_in[4];
    const void* Ws1  = d_in[5];
    const void* We2  = d_in[6];
    const void* Ws2  = d_in[7];
    const void* watt = d_in[8];

    char* ws = (char*)d_ws;
    const size_t SZ64 = (size_t)N_NODES * DOUT * sizeof(float);   // 12.8 MB
    const size_t NMSZ = (size_t)N_NODES * K_NBR * sizeof(float);  //  3.2 MB
    float* xn1 = (float*)(ws + 0 * SZ64);   // later reused as he1
    float* xn2 = (float*)(ws + 1 * SZ64);   // later reused as he2
    float* ag1 = (float*)(ws + 2 * SZ64);
    float* ag2 = (float*)(ws + 3 * SZ64);
    bf16*  h1  = (bf16*) (ws + 4 * SZ64);   // N*128 bf16 = 12.8 MB
    bf16*  h2  = (bf16*) (ws + 5 * SZ64);
    float* nm1 = (float*)(ws + 6 * SZ64);
    float* nm2 = (float*)(ws + 6 * SZ64 + NMSZ);
    int*  flag = (int*)  (ws + 6 * SZ64 + 2 * NMSZ);

    dim3 b(256);
    dim3 g4(N_NODES / 4, 2);                       // gather kernels: 1 wave/node
    dim3 gl((N_NODES + NPB - 1) / NPB, 2);         // linear kernels: 64 nodes/block

    detect_kernel<<<dim3(1), b, 0, stream>>>((const unsigned short*)x1, flag);
    lin1_kernel <<<gl, b, 0, stream>>>(x1, x2, We1, Ws1, xn1, xn2, h1, h2, flag);
    aggr1_kernel<<<g4, b, 0, stream>>>(nbr1, nbr2, xn1, xn2, ag1, ag2, h1, h2);
    attn_kernel <<<dim3(N_NODES), b, 0, stream>>>(nbr1, nbr2, ag1, ag2, watt, nm1, nm2, flag);
    lin2_kernel <<<gl, b, 0, stream>>>(h1, h2, We2, Ws2, xn1, xn2, d_out, flag);
    aggr2_kernel<<<g4, b, 0, stream>>>(nbr1, nbr2, xn1, xn2, nm1, nm2, d_out, flag);
}

// Round 2
// 459.593 us; speedup vs baseline: 1.6185x; 1.1861x over previous
//
#include <hip/hip_runtime.h>
#include <hip/hip_bf16.h>

#define N_NODES 50000
#define K_NBR   16
#define DIN     128
#define DOUT    64
#define NPB     64   // nodes per block in the linear kernels
#define NPW     16   // nodes per wave  (4 waves/block)

typedef __hip_bfloat16 bf16;

__device__ __forceinline__ float b2f(bf16 v) { return __bfloat162float(v); }
__device__ __forceinline__ float sigmoidf_(float x) { return 1.0f / (1.0f + __expf(-x)); }

template <typename T> __device__ __forceinline__ float ld(const T* p, size_t i);
template <> __device__ __forceinline__ float ld<float>(const float* p, size_t i) { return p[i]; }
template <> __device__ __forceinline__ float ld<bf16>(const bf16* p, size_t i)   { return b2f(p[i]); }

template <typename T> __device__ __forceinline__ void st(T* p, size_t i, float v);
template <> __device__ __forceinline__ void st<float>(float* p, size_t i, float v) { p[i] = v; }
template <> __device__ __forceinline__ void st<bf16>(bf16* p, size_t i, float v)   { p[i] = __float2bfloat16(v); }

// ---------------------------------------------------------------------------
// Dtype detector: view input as 16-bit words. For a true-bf16 array, the even
// (low-half-of-dword) elements are sane bf16 gaussians (exp in [112,142]).
// For an f32 array, low halves are mantissa garbage (~12% in range).
// flag: 1 = float32 data, 0 = bf16 data.
// ---------------------------------------------------------------------------
__global__ void detect_kernel(const unsigned short* __restrict__ x, int* __restrict__ flag)
{
    __shared__ int cnt;
    if (threadIdx.x == 0) cnt = 0;
    __syncthreads();
    int c = 0;
#pragma unroll
    for (int i = 0; i < 16; ++i) {
        unsigned short w = x[(size_t)(threadIdx.x * 16 + i) * 2];  // low half-word
        int e = (w >> 7) & 0xFF;
        c += (e >= 112 && e <= 142) ? 1 : 0;
    }
    atomicAdd(&cnt, c);
    __syncthreads();
    if (threadIdx.x == 0) *flag = (cnt >= 2048) ? 0 : 1;
}

// ---------------------------------------------------------------------------
// Node-blocked dual linear: xn = x @ We (f32), o[:, :64] = sigmoid(x @ Ws).
// 64 nodes per block staged in LDS (transposed, pad keeps float4 rows
// 16B-aligned). Each wave owns 16 nodes x 64 dims; weight loads amortized
// over 16 nodes.
// ---------------------------------------------------------------------------
template <typename TX, typename TW, typename TO>
__device__ __forceinline__ void lin_body(
    const TX* __restrict__ x, const TW* __restrict__ We, const TW* __restrict__ Ws,
    float* __restrict__ xn, TO* __restrict__ o)
{
    __shared__ __align__(16) float xs[DIN][NPB + 4];   // 34.8 KB -> 4 blocks/CU
    const int warp = threadIdx.x >> 6;
    const int lane = threadIdx.x & 63;
    const int nbase = blockIdx.x * NPB;

#pragma unroll 8
    for (int r = 0; r < 32; ++r) {
        int e  = threadIdx.x + 256 * r;   // 0..8191
        int nn = e >> 7;                  // 0..63
        int i  = e & 127;
        int n  = nbase + nn;
        if (n >= N_NODES) n = N_NODES - 1;
        xs[i][nn] = ld(x, (size_t)n * DIN + i);
    }
    __syncthreads();

    const int d  = lane;        // output dim
    const int nw = warp * NPW;  // this wave's first local node
    float accE[NPW], accS[NPW];
#pragma unroll
    for (int j = 0; j < NPW; ++j) { accE[j] = 0.f; accS[j] = 0.f; }

#pragma unroll 2
    for (int i = 0; i < DIN; ++i) {
        float we = ld(We, (size_t)i * DOUT + d);   // L1-resident, coalesced
        float ws = ld(Ws, (size_t)i * DOUT + d);
        const float4* __restrict__ xp = (const float4*)&xs[i][nw];  // broadcast reads
#pragma unroll
        for (int q = 0; q < NPW / 4; ++q) {
            float4 xv = xp[q];
            accE[4*q+0] += xv.x * we; accS[4*q+0] += xv.x * ws;
            accE[4*q+1] += xv.y * we; accS[4*q+1] += xv.y * ws;
            accE[4*q+2] += xv.z * we; accS[4*q+2] += xv.z * ws;
            accE[4*q+3] += xv.w * we; accS[4*q+3] += xv.w * ws;
        }
    }

#pragma unroll
    for (int j = 0; j < NPW; ++j) {
        int n = nbase + nw + j;
        if (n < N_NODES) {
            xn[(size_t)n * DOUT + d] = accE[j];                    // coalesced 256B
            st(o, (size_t)n * DIN + d, sigmoidf_(accS[j]));
        }
    }
}

__global__ __launch_bounds__(256) void lin1_kernel(
    const void* __restrict__ x1, const void* __restrict__ x2,
    const void* __restrict__ We, const void* __restrict__ Ws,
    float* __restrict__ xn1, float* __restrict__ xn2,
    bf16* __restrict__ h1, bf16* __restrict__ h2,
    const int* __restrict__ flag)
{
    const int g = blockIdx.y;
    const void* x  = g ? x2 : x1;
    float*      xn = g ? xn2 : xn1;
    bf16*       h  = g ? h2 : h1;
    if (*flag) lin_body<float, float, bf16>((const float*)x, (const float*)We, (const float*)Ws, xn, h);
    else       lin_body<bf16,  bf16,  bf16>((const bf16*)x,  (const bf16*)We,  (const bf16*)Ws,  xn, h);
}

// ---------------------------------------------------------------------------
// Pass B: aggr = (1/K) sum_k xn[nbr[n,k]] (f32), h[:, 64:] = sigmoid(aggr).
// NEW: while the aggregate row is in registers (lane = d), also reduce the
// three per-node scalars the attention pass needs:
//   qq[n]  = ||aggr||^2        (for d2 = q1[k]+q2[l]-2*dot)
//   slo[n] = aggr . w_att[:64] (self-attn dest term si)
//   shi[n] = aggr . w_att[64:] (self-attn src term sj, gathered per edge)
// This removes all per-edge recomputation of these dots in attn_kernel.
// ---------------------------------------------------------------------------
template <typename T>
__device__ __forceinline__ void aggr1_body(
    const int* __restrict__ nbr, const float* __restrict__ xn,
    float* __restrict__ ag, bf16* __restrict__ h, const T* __restrict__ watt,
    float* __restrict__ qq, float* __restrict__ slo, float* __restrict__ shi)
{
    const int warp = threadIdx.x >> 6;
    const int lane = threadIdx.x & 63;
    const int n = blockIdx.x * 4 + warp;

    int idx_l = nbr[n * K_NBR + (lane & 15)];
    float acc = 0.f;
#pragma unroll
    for (int k = 0; k < K_NBR; ++k) {
        int idx = __shfl(idx_l, k, 64);
        acc += xn[(size_t)idx * DOUT + lane];
    }
    acc *= (1.0f / K_NBR);
    ag[(size_t)n * DOUT + lane] = acc;
    h[(size_t)n * DIN + DOUT + lane] = __float2bfloat16(sigmoidf_(acc));

    float wl = ld(watt, lane);
    float wh = ld(watt, DOUT + lane);
    float pq = acc * acc;
    float pl = acc * wl;
    float ph = acc * wh;
#pragma unroll
    for (int off = 1; off < 64; off <<= 1) {
        pq += __shfl_xor(pq, off, 64);
        pl += __shfl_xor(pl, off, 64);
        ph += __shfl_xor(ph, off, 64);
    }
    if (lane == 0) { qq[n] = pq; slo[n] = pl; shi[n] = ph; }
}

__global__ __launch_bounds__(256) void aggr1_kernel(
    const int* __restrict__ nbr1, const int* __restrict__ nbr2,
    const float* __restrict__ xn1, const float* __restrict__ xn2,
    float* __restrict__ ag1, float* __restrict__ ag2,
    bf16* __restrict__ h1, bf16* __restrict__ h2,
    const void* __restrict__ watt,
    float* __restrict__ qq1, float* __restrict__ qq2,
    float* __restrict__ slo1, float* __restrict__ slo2,
    float* __restrict__ shi1, float* __restrict__ shi2,
    const int* __restrict__ flag)
{
    const int g = blockIdx.y;
    const int*   nbr = g ? nbr2 : nbr1;
    const float* xn  = g ? xn2 : xn1;
    float*       ag  = g ? ag2 : ag1;
    bf16*        h   = g ? h2 : h1;
    float* qq  = g ? qq2  : qq1;
    float* slo = g ? slo2 : slo1;
    float* shi = g ? shi2 : shi1;
    if (*flag) aggr1_body<float>(nbr, xn, ag, h, (const float*)watt, qq, slo, shi);
    else       aggr1_body<bf16>(nbr, xn, ag, h, (const bf16*)watt,  qq, slo, shi);
}

// ---------------------------------------------------------------------------
// Pass C: fused self-attn + cross-attn -> norm1/norm2 [N,K] (f32).
// ONE WAVE PER NODE (4 nodes/block, no __syncthreads). Lane = (k',l') in the
// 8x8 grid of 2x2 tiles of the 16x16 pair matrix. d2 via the norm trick
// (q1[k]+q2[l]-2*dot), cross-dots as float2 LDS reads with 2x2 register
// tiling (4 b64 reads amortized over 4 pairs), all reductions as full-wave
// shfl_xor butterflies. Rows padded to 66 floats: broadcast groups land on
// disjoint bank pairs (132*k' mod 32 = 4k').
// ---------------------------------------------------------------------------
__global__ __launch_bounds__(256) void attn_kernel(
    const int* __restrict__ nbr1, const int* __restrict__ nbr2,
    const float* __restrict__ ag1, const float* __restrict__ ag2,
    const float* __restrict__ qq1, const float* __restrict__ qq2,
    const float* __restrict__ slo1, const float* __restrict__ slo2,
    const float* __restrict__ shi1, const float* __restrict__ shi2,
    float* __restrict__ norm1, float* __restrict__ norm2)
{
    __shared__ __align__(8) float sa1[4][K_NBR][66];
    __shared__ __align__(8) float sa2[4][K_NBR][66];
    const int warp = threadIdx.x >> 6;
    const int lane = threadIdx.x & 63;
    const int n = blockIdx.x * 4 + warp;

    // lanes 0..15 hold nbr1 row, 16..31 hold nbr2 row
    int idxr = 0;
    if (lane < 32) {
        const int* nb = (lane < 16) ? nbr1 : nbr2;
        idxr = nb[n * K_NBR + (lane & 15)];
    }

    // gather 32 aggregate rows into this wave's LDS slice (coalesced 256B each)
#pragma unroll 4
    for (int k = 0; k < K_NBR; ++k) {
        int i1 = __shfl(idxr, k, 64);
        int i2 = __shfl(idxr, 16 + k, 64);
        sa1[warp][k][lane] = ag1[(size_t)i1 * DOUT + lane];
        sa2[warp][k][lane] = ag2[(size_t)i2 * DOUT + lane];
    }

    // per-edge scalars: lanes 0-15: q1[k], 16-31: q2[l], 32-47: shi1[k], 48-63: shi2[l]
    int myidx = __shfl(idxr, lane & 31, 64);
    const float* pa = (lane < 16) ? qq1 : (lane < 32) ? qq2 : (lane < 48) ? shi1 : shi2;
    float aux = pa[(size_t)myidx];

    // self-attn exp terms, lanes 0..31 meaningful
    float si  = (lane < 16) ? slo1[n] : slo2[n];
    float sjv = __shfl(aux, 32 + (lane & 31), 64);
    float v = si + sjv;
    v = v > 0.f ? v : 0.01f * v;
    float ev = __expf(v);
    float esum = ev;
#pragma unroll
    for (int off = 1; off < 16; off <<= 1) esum += __shfl_xor(esum, off, 64);
    // lanes 0..15: sum_e1; lanes 16..31: sum_e2

    // 2x2 tile of cross dot products
    const int kp = lane >> 3, lp = lane & 7;
    const float2* A0 = (const float2*)sa1[warp][2 * kp];
    const float2* A1 = (const float2*)sa1[warp][2 * kp + 1];
    const float2* B0 = (const float2*)sa2[warp][2 * lp];
    const float2* B1 = (const float2*)sa2[warp][2 * lp + 1];
    float d00 = 0.f, d01 = 0.f, d10 = 0.f, d11 = 0.f;
#pragma unroll 8
    for (int t = 0; t < DOUT / 2; ++t) {
        float2 a0 = A0[t], a1v = A1[t], b0 = B0[t], b1 = B1[t];
        d00 += a0.x  * b0.x; d00 += a0.y  * b0.y;
        d01 += a0.x  * b1.x; d01 += a0.y  * b1.y;
        d10 += a1v.x * b0.x; d10 += a1v.y * b0.y;
        d11 += a1v.x * b1.x; d11 += a1v.y * b1.y;
    }

    float q10 = __shfl(aux, 2 * kp, 64),      q11 = __shfl(aux, 2 * kp + 1, 64);
    float q20 = __shfl(aux, 16 + 2 * lp, 64), q21 = __shfl(aux, 16 + 2 * lp + 1, 64);
    float s00 = __expf(-sqrtf(fmaxf(q10 + q20 - 2.f * d00, 1e-12f)));
    float s01 = __expf(-sqrtf(fmaxf(q10 + q21 - 2.f * d01, 1e-12f)));
    float s10 = __expf(-sqrtf(fmaxf(q11 + q20 - 2.f * d10, 1e-12f)));
    float s11 = __expf(-sqrtf(fmaxf(q11 + q21 - 2.f * d11, 1e-12f)));

    // row sums over l (butterfly over lp), col sums over k (butterfly over kp)
    float r0 = s00 + s01, r1 = s10 + s11;
#pragma unroll
    for (int off = 1; off < 8; off <<= 1) { r0 += __shfl_xor(r0, off, 64); r1 += __shfl_xor(r1, off, 64); }
    float c0 = s00 + s10, c1 = s01 + s11;
#pragma unroll
    for (int off = 8; off < 64; off <<= 1) { c0 += __shfl_xor(c0, off, 64); c1 += __shfl_xor(c1, off, 64); }
    float tot = r0 + r1;
#pragma unroll
    for (int off = 8; off < 64; off <<= 1) tot += __shfl_xor(tot, off, 64);
    float rt = 1.0f / tot;

    // outputs: norm = (marginal/total) * (e/sum_e)
    float ek0 = __shfl(ev, 2 * kp, 64),      ek1 = __shfl(ev, 2 * kp + 1, 64);
    float se1 = __shfl(esum, 2 * kp, 64);
    float el0 = __shfl(ev, 16 + 2 * lp, 64), el1 = __shfl(ev, 16 + 2 * lp + 1, 64);
    float se2 = __shfl(esum, 16 + 2 * lp, 64);

    if (lp == 0) {
        float2 o; o.x = r0 * rt * ek0 / se1; o.y = r1 * rt * ek1 / se1;
        *(float2*)&norm1[(size_t)n * K_NBR + 2 * kp] = o;
    }
    if (kp == 0) {
        float2 o; o.x = c0 * rt * el0 / se2; o.y = c1 * rt * el1 / se2;
        *(float2*)&norm2[(size_t)n * K_NBR + 2 * lp] = o;
    }
}

// ---------------------------------------------------------------------------
// Pass D: he = h @ W_e2 (f32), out[:, :64] = sigmoid(h @ W_s2)
// Same node-blocked structure as lin1 (h is always bf16).
// ---------------------------------------------------------------------------
__global__ __launch_bounds__(256) void lin2_kernel(
    const bf16* __restrict__ h1, const bf16* __restrict__ h2,
    const void* __restrict__ We2, const void* __restrict__ Ws2,
    float* __restrict__ he1, float* __restrict__ he2,
    void* __restrict__ out, const int* __restrict__ flag)
{
    const int g = blockIdx.y;
    const bf16* h  = g ? h2 : h1;
    float*      he = g ? he2 : he1;
    if (*flag) lin_body<bf16, float, float>(h, (const float*)We2, (const float*)Ws2, he,
                                            (float*)out + (size_t)g * N_NODES * DIN);
    else       lin_body<bf16, bf16,  bf16 >(h, (const bf16*)We2,  (const bf16*)Ws2,  he,
                                            (bf16*)out + (size_t)g * N_NODES * DIN);
}

// ---------------------------------------------------------------------------
// Pass E: out[:, 64:] = sigmoid(sum_k norm[n,k] * he[nbr[n,k]])
// ---------------------------------------------------------------------------
template <typename T>
__device__ __forceinline__ void aggr2_body(
    const int* __restrict__ nbr, const float* __restrict__ he,
    const float* __restrict__ nm, T* __restrict__ o)
{
    const int warp = threadIdx.x >> 6;
    const int lane = threadIdx.x & 63;
    const int n = blockIdx.x * 4 + warp;

    int   idx_l = nbr[n * K_NBR + (lane & 15)];
    float w_l   = nm[n * K_NBR + (lane & 15)];
    float acc = 0.f;
#pragma unroll
    for (int k = 0; k < K_NBR; ++k) {
        int   idx = __shfl(idx_l, k, 64);
        float w   = __shfl(w_l, k, 64);
        acc += w * he[(size_t)idx * DOUT + lane];
    }
    st(o, (size_t)n * DIN + DOUT + lane, sigmoidf_(acc));
}

__global__ __launch_bounds__(256) void aggr2_kernel(
    const int* __restrict__ nbr1, const int* __restrict__ nbr2,
    const float* __restrict__ he1, const float* __restrict__ he2,
    const float* __restrict__ nm1, const float* __restrict__ nm2,
    void* __restrict__ out, const int* __restrict__ flag)
{
    const int g = blockIdx.y;
    const int*   nbr = g ? nbr2 : nbr1;
    const float* he  = g ? he2 : he1;
    const float* nm  = g ? nm2 : nm1;
    if (*flag) aggr2_body<float>(nbr, he, nm, (float*)out + (size_t)g * N_NODES * DIN);
    else       aggr2_body<bf16>(nbr, he, nm, (bf16*)out + (size_t)g * N_NODES * DIN);
}

// ---------------------------------------------------------------------------
extern "C" void kernel_launch(void* const* d_in, const int* in_sizes, int n_in,
                              void* d_out, int out_size, void* d_ws, size_t ws_size,
                              hipStream_t stream)
{
    const void* x1   = d_in[0];
    const void* x2   = d_in[1];
    const int*  nbr1 = (const int*)d_in[2];
    const int*  nbr2 = (const int*)d_in[3];
    const void* We1  = d_in[4];
    const void* Ws1  = d_in[5];
    const void* We2  = d_in[6];
    const void* Ws2  = d_in[7];
    const void* watt = d_in[8];

    char* ws = (char*)d_ws;
    const size_t SZ64 = (size_t)N_NODES * DOUT * sizeof(float);   // 12.8 MB
    const size_t NMSZ = (size_t)N_NODES * K_NBR * sizeof(float);  //  3.2 MB
    const size_t NSZ  = (size_t)N_NODES * sizeof(float);          //  0.2 MB
    float* xn1 = (float*)(ws + 0 * SZ64);   // later reused as he1
    float* xn2 = (float*)(ws + 1 * SZ64);   // later reused as he2
    float* ag1 = (float*)(ws + 2 * SZ64);
    float* ag2 = (float*)(ws + 3 * SZ64);
    bf16*  h1  = (bf16*) (ws + 4 * SZ64);   // N*128 bf16 = 12.8 MB
    bf16*  h2  = (bf16*) (ws + 5 * SZ64);
    float* nm1 = (float*)(ws + 6 * SZ64);
    float* nm2 = (float*)(ws + 6 * SZ64 + NMSZ);
    int*  flag = (int*)  (ws + 6 * SZ64 + 2 * NMSZ);
    char* aux  =         ws + 6 * SZ64 + 2 * NMSZ + 4096;
    float* qq1  = (float*)(aux + 0 * NSZ);
    float* qq2  = (float*)(aux + 1 * NSZ);
    float* slo1 = (float*)(aux + 2 * NSZ);
    float* slo2 = (float*)(aux + 3 * NSZ);
    float* shi1 = (float*)(aux + 4 * NSZ);
    float* shi2 = (float*)(aux + 5 * NSZ);

    dim3 b(256);
    dim3 g4(N_NODES / 4, 2);                       // gather kernels: 1 wave/node
    dim3 gl((N_NODES + NPB - 1) / NPB, 2);         // linear kernels: 64 nodes/block
    dim3 ga(N_NODES / 4);                          // attn: 4 node-waves/block

    detect_kernel<<<dim3(1), b, 0, stream>>>((const unsigned short*)x1, flag);
    lin1_kernel <<<gl, b, 0, stream>>>(x1, x2, We1, Ws1, xn1, xn2, h1, h2, flag);
    aggr1_kernel<<<g4, b, 0, stream>>>(nbr1, nbr2, xn1, xn2, ag1, ag2, h1, h2,
                                       watt, qq1, qq2, slo1, slo2, shi1, shi2, flag);
    attn_kernel <<<ga, b, 0, stream>>>(nbr1, nbr2, ag1, ag2, qq1, qq2,
                                       slo1, slo2, shi1, shi2, nm1, nm2);
    lin2_kernel <<<gl, b, 0, stream>>>(h1, h2, We2, Ws2, xn1, xn2, d_out, flag);
    aggr2_kernel<<<g4, b, 0, stream>>>(nbr1, nbr2, xn1, xn2, nm1, nm2, d_out, flag);
}

// Round 3
// 441.281 us; speedup vs baseline: 1.6856x; 1.0415x over previous
//
#include <hip/hip_runtime.h>
#include <hip/hip_bf16.h>

#define N_NODES 50000
#define K_NBR   16
#define DIN     128
#define DOUT    64
#define NPB     64   // nodes per block in the linear kernels
#define NPW     16   // nodes per wave  (f32 fallback path)

typedef __hip_bfloat16 bf16;
typedef __attribute__((ext_vector_type(8))) short bf16x8;
typedef __attribute__((ext_vector_type(4))) float f32x4;

#define LIN_SMEM 49152  // union: mfma path 48KB (xt 16K + wt 32K), f32 path 34.8KB

__device__ __forceinline__ float b2f(bf16 v) { return __bfloat162float(v); }
__device__ __forceinline__ float sigmoidf_(float x) { return 1.0f / (1.0f + __expf(-x)); }

template <typename T> __device__ __forceinline__ float ld(const T* p, size_t i);
template <> __device__ __forceinline__ float ld<float>(const float* p, size_t i) { return p[i]; }
template <> __device__ __forceinline__ float ld<bf16>(const bf16* p, size_t i)   { return b2f(p[i]); }

template <typename T> __device__ __forceinline__ void st(T* p, size_t i, float v);
template <> __device__ __forceinline__ void st<float>(float* p, size_t i, float v) { p[i] = v; }
template <> __device__ __forceinline__ void st<bf16>(bf16* p, size_t i, float v)   { p[i] = __float2bfloat16(v); }

// ---------------------------------------------------------------------------
// Dtype detector. flag: 1 = float32 data, 0 = bf16 data.
// (Round-2 counters: lin1 FETCH = 25.4 MB = N*DIN*2B*2 graphs -> data IS bf16;
//  the f32 path is retained for correctness only.)
// ---------------------------------------------------------------------------
__global__ void detect_kernel(const unsigned short* __restrict__ x, int* __restrict__ flag)
{
    __shared__ int cnt;
    if (threadIdx.x == 0) cnt = 0;
    __syncthreads();
    int c = 0;
#pragma unroll
    for (int i = 0; i < 16; ++i) {
        unsigned short w = x[(size_t)(threadIdx.x * 16 + i) * 2];  // low half-word
        int e = (w >> 7) & 0xFF;
        c += (e >= 112 && e <= 142) ? 1 : 0;
    }
    atomicAdd(&cnt, c);
    __syncthreads();
    if (threadIdx.x == 0) *flag = (cnt >= 2048) ? 0 : 1;
}

// ---------------------------------------------------------------------------
// Weight transpose pre-kernel: wtg[mat][d][k] (bf16, compact 64x128) from
// W[mat][k][d]. One block per mat; LDS bounce so global writes are coalesced.
// In f32 mode the output is unused (reads stay in bounds: 16KB of a 32KB buf).
// ---------------------------------------------------------------------------
__global__ __launch_bounds__(256) void wtrans_kernel(
    const void* __restrict__ Wa, const void* __restrict__ Wb,
    const void* __restrict__ Wc, const void* __restrict__ Wd,
    unsigned short* __restrict__ wtg)
{
    __shared__ unsigned short t[DIN][DOUT + 1];
    const unsigned short* W = (const unsigned short*)
        (blockIdx.x == 0 ? Wa : blockIdx.x == 1 ? Wb : blockIdx.x == 2 ? Wc : Wd);
    unsigned short* o = wtg + (size_t)blockIdx.x * DIN * DOUT;
#pragma unroll 8
    for (int it = 0; it < 32; ++it) {
        int idx = threadIdx.x + 256 * it;           // 8192 elems
        t[idx >> 6][idx & 63] = W[idx];             // coalesced read
    }
    __syncthreads();
#pragma unroll 8
    for (int it = 0; it < 32; ++it) {
        int idx = threadIdx.x + 256 * it;
        int d = idx >> 7, k = idx & 127;
        o[idx] = t[k][d];                           // coalesced write
    }
}

// ---------------------------------------------------------------------------
// MFMA dual linear (bf16 path): out_e = x @ We (f32), o[:, :64] = sigmoid(x@Ws).
// Block tile 64 nodes x 64 d, K=128. x-tile + transposed W tiles in LDS,
// 16B slots XOR-swizzled (slot c ^ (r&15)) so staging writes and fragment
// ds_read_b128s sit at the LDS return-bandwidth floor.
// Fragment layout (v_mfma_f32_16x16x32_bf16): A row = lane&15, k = (lane>>4)*8+j;
// B col = lane&15, same k; D col = lane&15, row = (lane>>4)*4 + reg (m89).
// ---------------------------------------------------------------------------
__device__ __forceinline__ void lin_mfma_body(
    const unsigned short* __restrict__ x,     // [N][128] bf16 rows
    const unsigned short* __restrict__ wt2,   // 2 mats of transposed W [d][k], 8192 each
    float* __restrict__ xn, bf16* __restrict__ o, char* smem)
{
    unsigned short* xt = (unsigned short*)smem;            // [64][128], swizzled slots
    unsigned short* wt = (unsigned short*)(smem + 16384);  // [2][64][128], swizzled
    const int tid = threadIdx.x;
    const int nbase = blockIdx.x * NPB;

    // stage x: 64 rows x 16 chunks of 16B, coalesced; tail rows clamped
#pragma unroll
    for (int it = 0; it < 4; ++it) {
        int idx = tid + 256 * it;
        int r = idx >> 4, c = idx & 15;
        int n = nbase + r; if (n >= N_NODES) n = N_NODES - 1;
        int4 v = *(const int4*)(x + (size_t)n * DIN + c * 8);
        *(int4*)(xt + r * DIN + ((c ^ (r & 15)) << 3)) = v;
    }
    // stage both weight mats: 2 x 64 rows x 16 chunks
#pragma unroll
    for (int it = 0; it < 8; ++it) {
        int idx = tid + 256 * it;
        int mt = idx >> 10, rem = idx & 1023;
        int r = rem >> 4, c = rem & 15;
        int4 v = *(const int4*)(wt2 + mt * 8192 + r * DIN + c * 8);
        *(int4*)(wt + mt * 8192 + r * DIN + ((c ^ (r & 15)) << 3)) = v;
    }
    __syncthreads();

    const int w = tid >> 6, lane = tid & 63;
    const int m = lane & 15, g = lane >> 4;

    f32x4 acc[2][4] = {};
    const unsigned short* xrow = xt + (w * 16 + m) * DIN;
#pragma unroll
    for (int ks = 0; ks < 4; ++ks) {
        int slot = ((ks * 4 + g) ^ m) << 3;        // 8-ushort slot offset
        bf16x8 a = *(const bf16x8*)(xrow + slot);
#pragma unroll
        for (int mt = 0; mt < 2; ++mt)
#pragma unroll
        for (int nc = 0; nc < 4; ++nc) {
            bf16x8 b = *(const bf16x8*)(wt + mt * 8192 + (nc * 16 + m) * DIN + slot);
            acc[mt][nc] = __builtin_amdgcn_mfma_f32_16x16x32_bf16(a, b, acc[mt][nc], 0, 0, 0);
        }
    }

#pragma unroll
    for (int nc = 0; nc < 4; ++nc) {
#pragma unroll
        for (int j = 0; j < 4; ++j) {
            int n = nbase + w * 16 + g * 4 + j;
            if (n < N_NODES) {
                int d = nc * 16 + m;
                xn[(size_t)n * DOUT + d] = acc[0][nc][j];
                o[(size_t)n * DIN + d] = __float2bfloat16(sigmoidf_(acc[1][nc][j]));
            }
        }
    }
}

// ---------------------------------------------------------------------------
// f32 fallback dual linear (round-2 scheme, LDS passed in to avoid the
// double-instantiation LDS blowup).
// ---------------------------------------------------------------------------
template <typename TX, typename TW, typename TO>
__device__ __forceinline__ void lin_body(
    const TX* __restrict__ x, const TW* __restrict__ We, const TW* __restrict__ Ws,
    float* __restrict__ xn, TO* __restrict__ o, char* smem)
{
    float (*xs)[NPB + 4] = (float (*)[NPB + 4])smem;   // [128][68]
    const int warp = threadIdx.x >> 6;
    const int lane = threadIdx.x & 63;
    const int nbase = blockIdx.x * NPB;

#pragma unroll 8
    for (int r = 0; r < 32; ++r) {
        int e  = threadIdx.x + 256 * r;
        int nn = e >> 7;
        int i  = e & 127;
        int n  = nbase + nn;
        if (n >= N_NODES) n = N_NODES - 1;
        xs[i][nn] = ld(x, (size_t)n * DIN + i);
    }
    __syncthreads();

    const int d  = lane;
    const int nw = warp * NPW;
    float accE[NPW], accS[NPW];
#pragma unroll
    for (int j = 0; j < NPW; ++j) { accE[j] = 0.f; accS[j] = 0.f; }

#pragma unroll 2
    for (int i = 0; i < DIN; ++i) {
        float we = ld(We, (size_t)i * DOUT + d);
        float ws = ld(Ws, (size_t)i * DOUT + d);
        const float4* __restrict__ xp = (const float4*)&xs[i][nw];
#pragma unroll
        for (int q = 0; q < NPW / 4; ++q) {
            float4 xv = xp[q];
            accE[4*q+0] += xv.x * we; accS[4*q+0] += xv.x * ws;
            accE[4*q+1] += xv.y * we; accS[4*q+1] += xv.y * ws;
            accE[4*q+2] += xv.z * we; accS[4*q+2] += xv.z * ws;
            accE[4*q+3] += xv.w * we; accS[4*q+3] += xv.w * ws;
        }
    }

#pragma unroll
    for (int j = 0; j < NPW; ++j) {
        int n = nbase + nw + j;
        if (n < N_NODES) {
            xn[(size_t)n * DOUT + d] = accE[j];
            st(o, (size_t)n * DIN + d, sigmoidf_(accS[j]));
        }
    }
}

__global__ __launch_bounds__(256) void lin1_kernel(
    const void* __restrict__ x1, const void* __restrict__ x2,
    const void* __restrict__ We, const void* __restrict__ Ws,
    const unsigned short* __restrict__ wtg,
    float* __restrict__ xn1, float* __restrict__ xn2,
    bf16* __restrict__ h1, bf16* __restrict__ h2,
    const int* __restrict__ flag)
{
    __shared__ __align__(16) char smem[LIN_SMEM];
    const int g = blockIdx.y;
    const void* x  = g ? x2 : x1;
    float*      xn = g ? xn2 : xn1;
    bf16*       h  = g ? h2 : h1;
    if (*flag) lin_body<float, float, bf16>((const float*)x, (const float*)We, (const float*)Ws, xn, h, smem);
    else       lin_mfma_body((const unsigned short*)x, wtg, xn, h, smem);
}

__global__ __launch_bounds__(256) void lin2_kernel(
    const bf16* __restrict__ h1, const bf16* __restrict__ h2,
    const void* __restrict__ We2, const void* __restrict__ Ws2,
    const unsigned short* __restrict__ wtg,
    float* __restrict__ he1, float* __restrict__ he2,
    void* __restrict__ out, const int* __restrict__ flag)
{
    __shared__ __align__(16) char smem[LIN_SMEM];
    const int g = blockIdx.y;
    const bf16* h  = g ? h2 : h1;
    float*      he = g ? he2 : he1;
    if (*flag) lin_body<bf16, float, float>(h, (const float*)We2, (const float*)Ws2, he,
                                            (float*)out + (size_t)g * N_NODES * DIN, smem);
    else       lin_mfma_body((const unsigned short*)h, wtg + 2 * 8192, he,
                             (bf16*)out + (size_t)g * N_NODES * DIN, smem);
}

// ---------------------------------------------------------------------------
// Pass B: aggr = (1/K) sum_k xn[nbr[n,k]] (f32), h[:, 64:] = sigmoid(aggr).
// Also reduces the per-node attention scalars qq/slo/shi (round-2).
// ---------------------------------------------------------------------------
template <typename T>
__device__ __forceinline__ void aggr1_body(
    const int* __restrict__ nbr, const float* __restrict__ xn,
    float* __restrict__ ag, bf16* __restrict__ h, const T* __restrict__ watt,
    float* __restrict__ qq, float* __restrict__ slo, float* __restrict__ shi)
{
    const int warp = threadIdx.x >> 6;
    const int lane = threadIdx.x & 63;
    const int n = blockIdx.x * 4 + warp;

    int idx_l = nbr[n * K_NBR + (lane & 15)];
    float acc = 0.f;
#pragma unroll
    for (int k = 0; k < K_NBR; ++k) {
        int idx = __shfl(idx_l, k, 64);
        acc += xn[(size_t)idx * DOUT + lane];
    }
    acc *= (1.0f / K_NBR);
    ag[(size_t)n * DOUT + lane] = acc;
    h[(size_t)n * DIN + DOUT + lane] = __float2bfloat16(sigmoidf_(acc));

    float wl = ld(watt, lane);
    float wh = ld(watt, DOUT + lane);
    float pq = acc * acc;
    float pl = acc * wl;
    float ph = acc * wh;
#pragma unroll
    for (int off = 1; off < 64; off <<= 1) {
        pq += __shfl_xor(pq, off, 64);
        pl += __shfl_xor(pl, off, 64);
        ph += __shfl_xor(ph, off, 64);
    }
    if (lane == 0) { qq[n] = pq; slo[n] = pl; shi[n] = ph; }
}

__global__ __launch_bounds__(256) void aggr1_kernel(
    const int* __restrict__ nbr1, const int* __restrict__ nbr2,
    const float* __restrict__ xn1, const float* __restrict__ xn2,
    float* __restrict__ ag1, float* __restrict__ ag2,
    bf16* __restrict__ h1, bf16* __restrict__ h2,
    const void* __restrict__ watt,
    float* __restrict__ qq1, float* __restrict__ qq2,
    float* __restrict__ slo1, float* __restrict__ slo2,
    float* __restrict__ shi1, float* __restrict__ shi2,
    const int* __restrict__ flag)
{
    const int g = blockIdx.y;
    const int*   nbr = g ? nbr2 : nbr1;
    const float* xn  = g ? xn2 : xn1;
    float*       ag  = g ? ag2 : ag1;
    bf16*        h   = g ? h2 : h1;
    float* qq  = g ? qq2  : qq1;
    float* slo = g ? slo2 : slo1;
    float* shi = g ? shi2 : shi1;
    if (*flag) aggr1_body<float>(nbr, xn, ag, h, (const float*)watt, qq, slo, shi);
    else       aggr1_body<bf16>(nbr, xn, ag, h, (const bf16*)watt,  qq, slo, shi);
}

// ---------------------------------------------------------------------------
// Pass C: fused self-attn + cross-attn -> norm1/norm2 [N,K] (f32).
// One wave per node (round-2 scheme).
// ---------------------------------------------------------------------------
__global__ __launch_bounds__(256) void attn_kernel(
    const int* __restrict__ nbr1, const int* __restrict__ nbr2,
    const float* __restrict__ ag1, const float* __restrict__ ag2,
    const float* __restrict__ qq1, const float* __restrict__ qq2,
    const float* __restrict__ slo1, const float* __restrict__ slo2,
    const float* __restrict__ shi1, const float* __restrict__ shi2,
    float* __restrict__ norm1, float* __restrict__ norm2)
{
    __shared__ __align__(8) float sa1[4][K_NBR][66];
    __shared__ __align__(8) float sa2[4][K_NBR][66];
    const int warp = threadIdx.x >> 6;
    const int lane = threadIdx.x & 63;
    const int n = blockIdx.x * 4 + warp;

    int idxr = 0;
    if (lane < 32) {
        const int* nb = (lane < 16) ? nbr1 : nbr2;
        idxr = nb[n * K_NBR + (lane & 15)];
    }

#pragma unroll 4
    for (int k = 0; k < K_NBR; ++k) {
        int i1 = __shfl(idxr, k, 64);
        int i2 = __shfl(idxr, 16 + k, 64);
        sa1[warp][k][lane] = ag1[(size_t)i1 * DOUT + lane];
        sa2[warp][k][lane] = ag2[(size_t)i2 * DOUT + lane];
    }

    int myidx = __shfl(idxr, lane & 31, 64);
    const float* pa = (lane < 16) ? qq1 : (lane < 32) ? qq2 : (lane < 48) ? shi1 : shi2;
    float aux = pa[(size_t)myidx];

    float si  = (lane < 16) ? slo1[n] : slo2[n];
    float sjv = __shfl(aux, 32 + (lane & 31), 64);
    float v = si + sjv;
    v = v > 0.f ? v : 0.01f * v;
    float ev = __expf(v);
    float esum = ev;
#pragma unroll
    for (int off = 1; off < 16; off <<= 1) esum += __shfl_xor(esum, off, 64);

    const int kp = lane >> 3, lp = lane & 7;
    const float2* A0 = (const float2*)sa1[warp][2 * kp];
    const float2* A1 = (const float2*)sa1[warp][2 * kp + 1];
    const float2* B0 = (const float2*)sa2[warp][2 * lp];
    const float2* B1 = (const float2*)sa2[warp][2 * lp + 1];
    float d00 = 0.f, d01 = 0.f, d10 = 0.f, d11 = 0.f;
#pragma unroll 8
    for (int t = 0; t < DOUT / 2; ++t) {
        float2 a0 = A0[t], a1v = A1[t], b0 = B0[t], b1 = B1[t];
        d00 += a0.x  * b0.x; d00 += a0.y  * b0.y;
        d01 += a0.x  * b1.x; d01 += a0.y  * b1.y;
        d10 += a1v.x * b0.x; d10 += a1v.y * b0.y;
        d11 += a1v.x * b1.x; d11 += a1v.y * b1.y;
    }

    float q10 = __shfl(aux, 2 * kp, 64),      q11 = __shfl(aux, 2 * kp + 1, 64);
    float q20 = __shfl(aux, 16 + 2 * lp, 64), q21 = __shfl(aux, 16 + 2 * lp + 1, 64);
    float s00 = __expf(-sqrtf(fmaxf(q10 + q20 - 2.f * d00, 1e-12f)));
    float s01 = __expf(-sqrtf(fmaxf(q10 + q21 - 2.f * d01, 1e-12f)));
    float s10 = __expf(-sqrtf(fmaxf(q11 + q20 - 2.f * d10, 1e-12f)));
    float s11 = __expf(-sqrtf(fmaxf(q11 + q21 - 2.f * d11, 1e-12f)));

    float r0 = s00 + s01, r1 = s10 + s11;
#pragma unroll
    for (int off = 1; off < 8; off <<= 1) { r0 += __shfl_xor(r0, off, 64); r1 += __shfl_xor(r1, off, 64); }
    float c0 = s00 + s10, c1 = s01 + s11;
#pragma unroll
    for (int off = 8; off < 64; off <<= 1) { c0 += __shfl_xor(c0, off, 64); c1 += __shfl_xor(c1, off, 64); }
    float tot = r0 + r1;
#pragma unroll
    for (int off = 8; off < 64; off <<= 1) tot += __shfl_xor(tot, off, 64);
    float rt = 1.0f / tot;

    float ek0 = __shfl(ev, 2 * kp, 64),      ek1 = __shfl(ev, 2 * kp + 1, 64);
    float se1 = __shfl(esum, 2 * kp, 64);
    float el0 = __shfl(ev, 16 + 2 * lp, 64), el1 = __shfl(ev, 16 + 2 * lp + 1, 64);
    float se2 = __shfl(esum, 16 + 2 * lp, 64);

    if (lp == 0) {
        float2 o; o.x = r0 * rt * ek0 / se1; o.y = r1 * rt * ek1 / se1;
        *(float2*)&norm1[(size_t)n * K_NBR + 2 * kp] = o;
    }
    if (kp == 0) {
        float2 o; o.x = c0 * rt * el0 / se2; o.y = c1 * rt * el1 / se2;
        *(float2*)&norm2[(size_t)n * K_NBR + 2 * lp] = o;
    }
}

// ---------------------------------------------------------------------------
// Pass E: out[:, 64:] = sigmoid(sum_k norm[n,k] * he[nbr[n,k]])
// ---------------------------------------------------------------------------
template <typename T>
__device__ __forceinline__ void aggr2_body(
    const int* __restrict__ nbr, const float* __restrict__ he,
    const float* __restrict__ nm, T* __restrict__ o)
{
    const int warp = threadIdx.x >> 6;
    const int lane = threadIdx.x & 63;
    const int n = blockIdx.x * 4 + warp;

    int   idx_l = nbr[n * K_NBR + (lane & 15)];
    float w_l   = nm[n * K_NBR + (lane & 15)];
    float acc = 0.f;
#pragma unroll
    for (int k = 0; k < K_NBR; ++k) {
        int   idx = __shfl(idx_l, k, 64);
        float w   = __shfl(w_l, k, 64);
        acc += w * he[(size_t)idx * DOUT + lane];
    }
    st(o, (size_t)n * DIN + DOUT + lane, sigmoidf_(acc));
}

__global__ __launch_bounds__(256) void aggr2_kernel(
    const int* __restrict__ nbr1, const int* __restrict__ nbr2,
    const float* __restrict__ he1, const float* __restrict__ he2,
    const float* __restrict__ nm1, const float* __restrict__ nm2,
    void* __restrict__ out, const int* __restrict__ flag)
{
    const int g = blockIdx.y;
    const int*   nbr = g ? nbr2 : nbr1;
    const float* he  = g ? he2 : he1;
    const float* nm  = g ? nm2 : nm1;
    if (*flag) aggr2_body<float>(nbr, he, nm, (float*)out + (size_t)g * N_NODES * DIN);
    else       aggr2_body<bf16>(nbr, he, nm, (bf16*)out + (size_t)g * N_NODES * DIN);
}

// ---------------------------------------------------------------------------
extern "C" void kernel_launch(void* const* d_in, const int* in_sizes, int n_in,
                              void* d_out, int out_size, void* d_ws, size_t ws_size,
                              hipStream_t stream)
{
    const void* x1   = d_in[0];
    const void* x2   = d_in[1];
    const int*  nbr1 = (const int*)d_in[2];
    const int*  nbr2 = (const int*)d_in[3];
    const void* We1  = d_in[4];
    const void* Ws1  = d_in[5];
    const void* We2  = d_in[6];
    const void* Ws2  = d_in[7];
    const void* watt = d_in[8];

    char* ws = (char*)d_ws;
    const size_t SZ64 = (size_t)N_NODES * DOUT * sizeof(float);   // 12.8 MB
    const size_t NMSZ = (size_t)N_NODES * K_NBR * sizeof(float);  //  3.2 MB
    const size_t NSZ  = (size_t)N_NODES * sizeof(float);          //  0.2 MB
    float* xn1 = (float*)(ws + 0 * SZ64);   // later reused as he1
    float* xn2 = (float*)(ws + 1 * SZ64);   // later reused as he2
    float* ag1 = (float*)(ws + 2 * SZ64);
    float* ag2 = (float*)(ws + 3 * SZ64);
    bf16*  h1  = (bf16*) (ws + 4 * SZ64);   // N*128 bf16 = 12.8 MB
    bf16*  h2  = (bf16*) (ws + 5 * SZ64);
    float* nm1 = (float*)(ws + 6 * SZ64);
    float* nm2 = (float*)(ws + 6 * SZ64 + NMSZ);
    int*  flag = (int*)  (ws + 6 * SZ64 + 2 * NMSZ);
    char* aux  =         ws + 6 * SZ64 + 2 * NMSZ + 4096;
    float* qq1  = (float*)(aux + 0 * NSZ);
    float* qq2  = (float*)(aux + 1 * NSZ);
    float* slo1 = (float*)(aux + 2 * NSZ);
    float* slo2 = (float*)(aux + 3 * NSZ);
    float* shi1 = (float*)(aux + 4 * NSZ);
    float* shi2 = (float*)(aux + 5 * NSZ);
    unsigned short* wtg = (unsigned short*)(aux + 6 * NSZ);  // 4 x 16KB transposed W

    dim3 b(256);
    dim3 g4(N_NODES / 4, 2);                       // gather kernels: 1 wave/node
    dim3 gl((N_NODES + NPB - 1) / NPB, 2);         // linear kernels: 64 nodes/block
    dim3 ga(N_NODES / 4);                          // attn: 4 node-waves/block

    detect_kernel<<<dim3(1), b, 0, stream>>>((const unsigned short*)x1, flag);
    wtrans_kernel<<<dim3(4), b, 0, stream>>>(We1, Ws1, We2, Ws2, wtg);
    lin1_kernel <<<gl, b, 0, stream>>>(x1, x2, We1, Ws1, wtg, xn1, xn2, h1, h2, flag);
    aggr1_kernel<<<g4, b, 0, stream>>>(nbr1, nbr2, xn1, xn2, ag1, ag2, h1, h2,
                                       watt, qq1, qq2, slo1, slo2, shi1, shi2, flag);
    attn_kernel <<<ga, b, 0, stream>>>(nbr1, nbr2, ag1, ag2, qq1, qq2,
                                       slo1, slo2, shi1, shi2, nm1, nm2);
    lin2_kernel <<<gl, b, 0, stream>>>(h1, h2, We2, Ws2, wtg, xn1, xn2, d_out, flag);
    aggr2_kernel<<<g4, b, 0, stream>>>(nbr1, nbr2, xn1, xn2, nm1, nm2, d_out, flag);
}

// Round 4
// 355.278 us; speedup vs baseline: 2.0937x; 1.2421x over previous
//
#include <hip/hip_runtime.h>
#include <hip/hip_bf16.h>

#define N_NODES 50000
#define K_NBR   16
#define DIN     128
#define DOUT    64
#define NPB     64   // nodes per block in the linear kernels
#define NPW     16   // nodes per wave  (f32 fallback path)

typedef __hip_bfloat16 bf16;
typedef __attribute__((ext_vector_type(8))) short bf16x8;
typedef __attribute__((ext_vector_type(4))) float f32x4;

#define LIN_SMEM 49152  // union: mfma path 48KB (xt 16K + wt 32K), f32 path 34.8KB

__device__ __forceinline__ float b2f(bf16 v) { return __bfloat162float(v); }
__device__ __forceinline__ float sigmoidf_(float x) { return 1.0f / (1.0f + __expf(-x)); }

template <typename T> __device__ __forceinline__ float ld(const T* p, size_t i);
template <> __device__ __forceinline__ float ld<float>(const float* p, size_t i) { return p[i]; }
template <> __device__ __forceinline__ float ld<bf16>(const bf16* p, size_t i)   { return b2f(p[i]); }

template <typename T> __device__ __forceinline__ void st(T* p, size_t i, float v);
template <> __device__ __forceinline__ void st<float>(float* p, size_t i, float v) { p[i] = v; }
template <> __device__ __forceinline__ void st<bf16>(bf16* p, size_t i, float v)   { p[i] = __float2bfloat16(v); }

// ---------------------------------------------------------------------------
// Dtype detector. flag: 1 = float32 data, 0 = bf16 data.
// (lin1 FETCH = 25.4 MB = N*DIN*2B*2 graphs -> bench data IS bf16.)
// ---------------------------------------------------------------------------
__global__ void detect_kernel(const unsigned short* __restrict__ x, int* __restrict__ flag)
{
    __shared__ int cnt;
    if (threadIdx.x == 0) cnt = 0;
    __syncthreads();
    int c = 0;
#pragma unroll
    for (int i = 0; i < 16; ++i) {
        unsigned short w = x[(size_t)(threadIdx.x * 16 + i) * 2];  // low half-word
        int e = (w >> 7) & 0xFF;
        c += (e >= 112 && e <= 142) ? 1 : 0;
    }
    atomicAdd(&cnt, c);
    __syncthreads();
    if (threadIdx.x == 0) *flag = (cnt >= 2048) ? 0 : 1;
}

// ---------------------------------------------------------------------------
// Weight transpose pre-kernel: wtg[mat][d][k] (bf16, compact 64x128) from
// W[mat][k][d]. One block per mat; LDS bounce so global writes are coalesced.
// ---------------------------------------------------------------------------
__global__ __launch_bounds__(256) void wtrans_kernel(
    const void* __restrict__ Wa, const void* __restrict__ Wb,
    const void* __restrict__ Wc, const void* __restrict__ Wd,
    unsigned short* __restrict__ wtg)
{
    __shared__ unsigned short t[DIN][DOUT + 1];
    const unsigned short* W = (const unsigned short*)
        (blockIdx.x == 0 ? Wa : blockIdx.x == 1 ? Wb : blockIdx.x == 2 ? Wc : Wd);
    unsigned short* o = wtg + (size_t)blockIdx.x * DIN * DOUT;
#pragma unroll 8
    for (int it = 0; it < 32; ++it) {
        int idx = threadIdx.x + 256 * it;           // 8192 elems
        t[idx >> 6][idx & 63] = W[idx];             // coalesced read
    }
    __syncthreads();
#pragma unroll 8
    for (int it = 0; it < 32; ++it) {
        int idx = threadIdx.x + 256 * it;
        int d = idx >> 7, k = idx & 127;
        o[idx] = t[k][d];                           // coalesced write
    }
}

// ---------------------------------------------------------------------------
// MFMA dual linear (bf16 path): xnh = bf16(x @ We), o[:, :64] = sigmoid(x@Ws).
// Block tile 64 nodes x 64 d, K=128; XOR-swizzled LDS slots (round 3, verified).
// xnh now stored bf16 to halve the downstream gather traffic.
// ---------------------------------------------------------------------------
__device__ __forceinline__ void lin_mfma_body(
    const unsigned short* __restrict__ x,     // [N][128] bf16 rows
    const unsigned short* __restrict__ wt2,   // 2 mats of transposed W [d][k]
    bf16* __restrict__ xnh, bf16* __restrict__ o, char* smem)
{
    unsigned short* xt = (unsigned short*)smem;            // [64][128], swizzled slots
    unsigned short* wt = (unsigned short*)(smem + 16384);  // [2][64][128], swizzled
    const int tid = threadIdx.x;
    const int nbase = blockIdx.x * NPB;

#pragma unroll
    for (int it = 0; it < 4; ++it) {
        int idx = tid + 256 * it;
        int r = idx >> 4, c = idx & 15;
        int n = nbase + r; if (n >= N_NODES) n = N_NODES - 1;
        int4 v = *(const int4*)(x + (size_t)n * DIN + c * 8);
        *(int4*)(xt + r * DIN + ((c ^ (r & 15)) << 3)) = v;
    }
#pragma unroll
    for (int it = 0; it < 8; ++it) {
        int idx = tid + 256 * it;
        int mt = idx >> 10, rem = idx & 1023;
        int r = rem >> 4, c = rem & 15;
        int4 v = *(const int4*)(wt2 + mt * 8192 + r * DIN + c * 8);
        *(int4*)(wt + mt * 8192 + r * DIN + ((c ^ (r & 15)) << 3)) = v;
    }
    __syncthreads();

    const int w = tid >> 6, lane = tid & 63;
    const int m = lane & 15, g = lane >> 4;

    f32x4 acc[2][4] = {};
    const unsigned short* xrow = xt + (w * 16 + m) * DIN;
#pragma unroll
    for (int ks = 0; ks < 4; ++ks) {
        int slot = ((ks * 4 + g) ^ m) << 3;
        bf16x8 a = *(const bf16x8*)(xrow + slot);
#pragma unroll
        for (int mt = 0; mt < 2; ++mt)
#pragma unroll
        for (int nc = 0; nc < 4; ++nc) {
            bf16x8 b = *(const bf16x8*)(wt + mt * 8192 + (nc * 16 + m) * DIN + slot);
            acc[mt][nc] = __builtin_amdgcn_mfma_f32_16x16x32_bf16(a, b, acc[mt][nc], 0, 0, 0);
        }
    }

#pragma unroll
    for (int nc = 0; nc < 4; ++nc) {
#pragma unroll
        for (int j = 0; j < 4; ++j) {
            int n = nbase + w * 16 + g * 4 + j;
            if (n < N_NODES) {
                int d = nc * 16 + m;
                xnh[(size_t)n * DOUT + d] = __float2bfloat16(acc[0][nc][j]);
                o[(size_t)n * DIN + d] = __float2bfloat16(sigmoidf_(acc[1][nc][j]));
            }
        }
    }
}

// ---------------------------------------------------------------------------
// f32 fallback dual linear (intermediates still written bf16).
// ---------------------------------------------------------------------------
template <typename TX, typename TW, typename TO>
__device__ __forceinline__ void lin_body(
    const TX* __restrict__ x, const TW* __restrict__ We, const TW* __restrict__ Ws,
    bf16* __restrict__ xnh, TO* __restrict__ o, char* smem)
{
    float (*xs)[NPB + 4] = (float (*)[NPB + 4])smem;   // [128][68]
    const int warp = threadIdx.x >> 6;
    const int lane = threadIdx.x & 63;
    const int nbase = blockIdx.x * NPB;

#pragma unroll 8
    for (int r = 0; r < 32; ++r) {
        int e  = threadIdx.x + 256 * r;
        int nn = e >> 7;
        int i  = e & 127;
        int n  = nbase + nn;
        if (n >= N_NODES) n = N_NODES - 1;
        xs[i][nn] = ld(x, (size_t)n * DIN + i);
    }
    __syncthreads();

    const int d  = lane;
    const int nw = warp * NPW;
    float accE[NPW], accS[NPW];
#pragma unroll
    for (int j = 0; j < NPW; ++j) { accE[j] = 0.f; accS[j] = 0.f; }

#pragma unroll 2
    for (int i = 0; i < DIN; ++i) {
        float we = ld(We, (size_t)i * DOUT + d);
        float ws = ld(Ws, (size_t)i * DOUT + d);
        const float4* __restrict__ xp = (const float4*)&xs[i][nw];
#pragma unroll
        for (int q = 0; q < NPW / 4; ++q) {
            float4 xv = xp[q];
            accE[4*q+0] += xv.x * we; accS[4*q+0] += xv.x * ws;
            accE[4*q+1] += xv.y * we; accS[4*q+1] += xv.y * ws;
            accE[4*q+2] += xv.z * we; accS[4*q+2] += xv.z * ws;
            accE[4*q+3] += xv.w * we; accS[4*q+3] += xv.w * ws;
        }
    }

#pragma unroll
    for (int j = 0; j < NPW; ++j) {
        int n = nbase + nw + j;
        if (n < N_NODES) {
            xnh[(size_t)n * DOUT + d] = __float2bfloat16(accE[j]);
            st(o, (size_t)n * DIN + d, sigmoidf_(accS[j]));
        }
    }
}

__global__ __launch_bounds__(256) void lin1_kernel(
    const void* __restrict__ x1, const void* __restrict__ x2,
    const void* __restrict__ We, const void* __restrict__ Ws,
    const unsigned short* __restrict__ wtg,
    bf16* __restrict__ xnh1, bf16* __restrict__ xnh2,
    bf16* __restrict__ h1, bf16* __restrict__ h2,
    const int* __restrict__ flag)
{
    __shared__ __align__(16) char smem[LIN_SMEM];
    const int g = blockIdx.y;
    const void* x   = g ? x2 : x1;
    bf16*       xnh = g ? xnh2 : xnh1;
    bf16*       h   = g ? h2 : h1;
    if (*flag) lin_body<float, float, bf16>((const float*)x, (const float*)We, (const float*)Ws, xnh, h, smem);
    else       lin_mfma_body((const unsigned short*)x, wtg, xnh, h, smem);
}

__global__ __launch_bounds__(256) void lin2_kernel(
    const bf16* __restrict__ h1, const bf16* __restrict__ h2,
    const void* __restrict__ We2, const void* __restrict__ Ws2,
    const unsigned short* __restrict__ wtg,
    bf16* __restrict__ heh1, bf16* __restrict__ heh2,
    void* __restrict__ out, const int* __restrict__ flag)
{
    __shared__ __align__(16) char smem[LIN_SMEM];
    const int g = blockIdx.y;
    const bf16* h   = g ? h2 : h1;
    bf16*       heh = g ? heh2 : heh1;
    if (*flag) lin_body<bf16, float, float>(h, (const float*)We2, (const float*)Ws2, heh,
                                            (float*)out + (size_t)g * N_NODES * DIN, smem);
    else       lin_mfma_body((const unsigned short*)h, wtg + 2 * 8192, heh,
                             (bf16*)out + (size_t)g * N_NODES * DIN, smem);
}

// ---------------------------------------------------------------------------
// Pass B: aggr = (1/K) sum_k xnh[nbr[n,k]] (bf16 gather, f32 accumulate).
// Writes agh = bf16(aggr) + h[:, 64:] = sigmoid(aggr) + per-node scalars
// qq (from the ROUNDED aggregate, so attn's d2 = |a1-a2|^2 >= 0 exactly),
// slo/shi (full precision, self-attn only).
// ---------------------------------------------------------------------------
template <typename T>
__device__ __forceinline__ void aggr1_body(
    const int* __restrict__ nbr, const bf16* __restrict__ xnh,
    bf16* __restrict__ agh, bf16* __restrict__ h, const T* __restrict__ watt,
    float* __restrict__ qq, float* __restrict__ slo, float* __restrict__ shi)
{
    const int warp = threadIdx.x >> 6;
    const int lane = threadIdx.x & 63;
    const int n = blockIdx.x * 4 + warp;

    int idx_l = nbr[n * K_NBR + (lane & 15)];
    float acc = 0.f;
#pragma unroll
    for (int k = 0; k < K_NBR; ++k) {
        int idx = __shfl(idx_l, k, 64);
        acc += b2f(xnh[(size_t)idx * DOUT + lane]);
    }
    acc *= (1.0f / K_NBR);
    bf16 av16 = __float2bfloat16(acc);
    float av = b2f(av16);
    agh[(size_t)n * DOUT + lane] = av16;
    h[(size_t)n * DIN + DOUT + lane] = __float2bfloat16(sigmoidf_(acc));

    float wl = ld(watt, lane);
    float wh = ld(watt, DOUT + lane);
    float pq = av * av;
    float pl = acc * wl;
    float ph = acc * wh;
#pragma unroll
    for (int off = 1; off < 64; off <<= 1) {
        pq += __shfl_xor(pq, off, 64);
        pl += __shfl_xor(pl, off, 64);
        ph += __shfl_xor(ph, off, 64);
    }
    if (lane == 0) { qq[n] = pq; slo[n] = pl; shi[n] = ph; }
}

__global__ __launch_bounds__(256) void aggr1_kernel(
    const int* __restrict__ nbr1, const int* __restrict__ nbr2,
    const bf16* __restrict__ xnh1, const bf16* __restrict__ xnh2,
    bf16* __restrict__ agh1, bf16* __restrict__ agh2,
    bf16* __restrict__ h1, bf16* __restrict__ h2,
    const void* __restrict__ watt,
    float* __restrict__ qq1, float* __restrict__ qq2,
    float* __restrict__ slo1, float* __restrict__ slo2,
    float* __restrict__ shi1, float* __restrict__ shi2,
    const int* __restrict__ flag)
{
    const int g = blockIdx.y;
    const int*  nbr = g ? nbr2 : nbr1;
    const bf16* xnh = g ? xnh2 : xnh1;
    bf16*       agh = g ? agh2 : agh1;
    bf16*       h   = g ? h2 : h1;
    float* qq  = g ? qq2  : qq1;
    float* slo = g ? slo2 : slo1;
    float* shi = g ? shi2 : shi1;
    if (*flag) aggr1_body<float>(nbr, xnh, agh, h, (const float*)watt, qq, slo, shi);
    else       aggr1_body<bf16>(nbr, xnh, agh, h, (const bf16*)watt,  qq, slo, shi);
}

// ---------------------------------------------------------------------------
// Pass C: fused self-attn + cross-attn -> norm1/norm2 [N,K] (f32).
// One wave per node, ZERO LDS. The 16x16 dot matrix is 2 MFMAs whose A/B
// fragments gather 16B chunks straight from global bf16 agh rows
// (lane(g,m): A row idx1[m], B col idx2[m], k-chunk g*8..g*8+7).
// D layout (m89): col = lane&15 (= l2), row = g*4+reg (= k1).
// Each 128B row fetched exactly once -> 4KB/node, the gather minimum.
// ---------------------------------------------------------------------------
__global__ __launch_bounds__(256) void attn_kernel(
    const int* __restrict__ nbr1, const int* __restrict__ nbr2,
    const unsigned short* __restrict__ agh1, const unsigned short* __restrict__ agh2,
    const float* __restrict__ qq1, const float* __restrict__ qq2,
    const float* __restrict__ slo1, const float* __restrict__ slo2,
    const float* __restrict__ shi1, const float* __restrict__ shi2,
    float* __restrict__ norm1, float* __restrict__ norm2)
{
    const int warp = threadIdx.x >> 6;
    const int lane = threadIdx.x & 63;
    const int n = blockIdx.x * 4 + warp;
    const int m = lane & 15, g = lane >> 4;

    int idxr = 0;
    if (lane < 32) idxr = ((lane < 16) ? nbr1 : nbr2)[n * K_NBR + m];

    const int i1 = __shfl(idxr, m, 64);
    const int i2 = __shfl(idxr, 16 + m, 64);

    // fragment gathers (16B per lane, 2 chunks cover the 128B row)
    const bf16x8* a1p = (const bf16x8*)(agh1 + (size_t)i1 * DOUT + g * 8);
    const bf16x8* a2p = (const bf16x8*)(agh2 + (size_t)i2 * DOUT + g * 8);
    bf16x8 aA = a1p[0], aB = a1p[4];   // dims 0..31, 32..63 (row i1)
    bf16x8 bA = a2p[0], bB = a2p[4];   // dims 0..31, 32..63 (row i2)

    // per-edge scalars: lanes 0-15: qq1[i1], 16-31: qq2[i2], 32-47: shi1, 48-63: shi2
    int myidx = __shfl(idxr, lane & 31, 64);
    const float* pa = (lane < 16) ? qq1 : (lane < 32) ? qq2 : (lane < 48) ? shi1 : shi2;
    float aux = pa[(size_t)myidx];

    // self-attn exp terms (lanes 0..31 meaningful)
    float si  = (lane < 16) ? slo1[n] : slo2[n];
    float sjv = __shfl(aux, 32 + (lane & 31), 64);
    float v = si + sjv;
    v = v > 0.f ? v : 0.01f * v;
    float ev = __expf(v);
    float esum = ev;
#pragma unroll
    for (int off = 1; off < 16; off <<= 1) esum += __shfl_xor(esum, off, 64);

    // 16x16 dots: D[k1 = g*4+r][l2 = m]
    f32x4 acc = {};
    acc = __builtin_amdgcn_mfma_f32_16x16x32_bf16(aA, bA, acc, 0, 0, 0);
    acc = __builtin_amdgcn_mfma_f32_16x16x32_bf16(aB, bB, acc, 0, 0, 0);

    float q2c = __shfl(aux, 16 + m, 64);
    float s0, s1, s2, s3;
    {
        float q10 = __shfl(aux, g * 4 + 0, 64);
        float q11 = __shfl(aux, g * 4 + 1, 64);
        float q12 = __shfl(aux, g * 4 + 2, 64);
        float q13 = __shfl(aux, g * 4 + 3, 64);
        s0 = __expf(-sqrtf(fmaxf(q10 + q2c - 2.f * acc[0], 1e-12f)));
        s1 = __expf(-sqrtf(fmaxf(q11 + q2c - 2.f * acc[1], 1e-12f)));
        s2 = __expf(-sqrtf(fmaxf(q12 + q2c - 2.f * acc[2], 1e-12f)));
        s3 = __expf(-sqrtf(fmaxf(q13 + q2c - 2.f * acc[3], 1e-12f)));
    }

    float c = s0 + s1 + s2 + s3;            // partial col sum (4 rows of group g)
#pragma unroll
    for (int off = 1; off < 16; off <<= 1) {  // row sums over l (= m)
        s0 += __shfl_xor(s0, off, 64);
        s1 += __shfl_xor(s1, off, 64);
        s2 += __shfl_xor(s2, off, 64);
        s3 += __shfl_xor(s3, off, 64);
    }
    float cs = c;                            // col sums over k (= across groups)
    cs += __shfl_xor(cs, 16, 64);
    cs += __shfl_xor(cs, 32, 64);
    float tot = cs;
#pragma unroll
    for (int off = 1; off < 16; off <<= 1) tot += __shfl_xor(tot, off, 64);
    float rt = 1.0f / tot;

    // norm2: lane 16+m holds cs[m], ev=e2[m], esum=sum_e2
    if (g == 1) norm2[(size_t)n * K_NBR + m] = cs * rt * ev / esum;

    // norm1: bring rs[m] to lane m (g==0): rs[row] lives in reg row&3 of group row>>2
    float r0 = __shfl(s0, (m >> 2) << 4, 64);
    float r1 = __shfl(s1, (m >> 2) << 4, 64);
    float r2 = __shfl(s2, (m >> 2) << 4, 64);
    float r3 = __shfl(s3, (m >> 2) << 4, 64);
    int mr = m & 3;
    float rsm = mr == 0 ? r0 : mr == 1 ? r1 : mr == 2 ? r2 : r3;
    if (g == 0) norm1[(size_t)n * K_NBR + m] = rsm * rt * ev / esum;
}

// ---------------------------------------------------------------------------
// Pass E: out[:, 64:] = sigmoid(sum_k norm[n,k] * heh[nbr[n,k]]) (bf16 gather)
// ---------------------------------------------------------------------------
template <typename T>
__device__ __forceinline__ void aggr2_body(
    const int* __restrict__ nbr, const bf16* __restrict__ heh,
    const float* __restrict__ nm, T* __restrict__ o)
{
    const int warp = threadIdx.x >> 6;
    const int lane = threadIdx.x & 63;
    const int n = blockIdx.x * 4 + warp;

    int   idx_l = nbr[n * K_NBR + (lane & 15)];
    float w_l   = nm[n * K_NBR + (lane & 15)];
    float acc = 0.f;
#pragma unroll
    for (int k = 0; k < K_NBR; ++k) {
        int   idx = __shfl(idx_l, k, 64);
        float w   = __shfl(w_l, k, 64);
        acc += w * b2f(heh[(size_t)idx * DOUT + lane]);
    }
    st(o, (size_t)n * DIN + DOUT + lane, sigmoidf_(acc));
}

__global__ __launch_bounds__(256) void aggr2_kernel(
    const int* __restrict__ nbr1, const int* __restrict__ nbr2,
    const bf16* __restrict__ heh1, const bf16* __restrict__ heh2,
    const float* __restrict__ nm1, const float* __restrict__ nm2,
    void* __restrict__ out, const int* __restrict__ flag)
{
    const int g = blockIdx.y;
    const int*  nbr = g ? nbr2 : nbr1;
    const bf16* heh = g ? heh2 : heh1;
    const float* nm = g ? nm2 : nm1;
    if (*flag) aggr2_body<float>(nbr, heh, nm, (float*)out + (size_t)g * N_NODES * DIN);
    else       aggr2_body<bf16>(nbr, heh, nm, (bf16*)out + (size_t)g * N_NODES * DIN);
}

// ---------------------------------------------------------------------------
extern "C" void kernel_launch(void* const* d_in, const int* in_sizes, int n_in,
                              void* d_out, int out_size, void* d_ws, size_t ws_size,
                              hipStream_t stream)
{
    const void* x1   = d_in[0];
    const void* x2   = d_in[1];
    const int*  nbr1 = (const int*)d_in[2];
    const int*  nbr2 = (const int*)d_in[3];
    const void* We1  = d_in[4];
    const void* Ws1  = d_in[5];
    const void* We2  = d_in[6];
    const void* Ws2  = d_in[7];
    const void* watt = d_in[8];

    char* ws = (char*)d_ws;
    const size_t SZH  = (size_t)N_NODES * DOUT * sizeof(bf16);   // 6.4 MB
    const size_t HSZ  = (size_t)N_NODES * DIN * sizeof(bf16);    // 12.8 MB
    const size_t NMSZ = (size_t)N_NODES * K_NBR * sizeof(float); //  3.2 MB
    const size_t NSZ  = (size_t)N_NODES * sizeof(float);         //  0.2 MB
    bf16* xnh1 = (bf16*)(ws + 0 * SZH);   // later reused as heh1
    bf16* xnh2 = (bf16*)(ws + 1 * SZH);   // later reused as heh2
    bf16* agh1 = (bf16*)(ws + 2 * SZH);
    bf16* agh2 = (bf16*)(ws + 3 * SZH);
    bf16* h1   = (bf16*)(ws + 4 * SZH);
    bf16* h2   = (bf16*)(ws + 4 * SZH + HSZ);
    char* p    =         ws + 4 * SZH + 2 * HSZ;
    float* nm1 = (float*)(p);
    float* nm2 = (float*)(p + NMSZ);
    int*  flag = (int*)  (p + 2 * NMSZ);
    char* aux  =          p + 2 * NMSZ + 4096;
    float* qq1  = (float*)(aux + 0 * NSZ);
    float* qq2  = (float*)(aux + 1 * NSZ);
    float* slo1 = (float*)(aux + 2 * NSZ);
    float* slo2 = (float*)(aux + 3 * NSZ);
    float* shi1 = (float*)(aux + 4 * NSZ);
    float* shi2 = (float*)(aux + 5 * NSZ);
    unsigned short* wtg = (unsigned short*)(aux + 6 * NSZ);  // 4 x 16KB transposed W

    dim3 b(256);
    dim3 g4(N_NODES / 4, 2);                       // gather kernels: 1 wave/node
    dim3 gl((N_NODES + NPB - 1) / NPB, 2);         // linear kernels: 64 nodes/block
    dim3 ga(N_NODES / 4);                          // attn: 4 node-waves/block

    detect_kernel<<<dim3(1), b, 0, stream>>>((const unsigned short*)x1, flag);
    wtrans_kernel<<<dim3(4), b, 0, stream>>>(We1, Ws1, We2, Ws2, wtg);
    lin1_kernel <<<gl, b, 0, stream>>>(x1, x2, We1, Ws1, wtg, xnh1, xnh2, h1, h2, flag);
    aggr1_kernel<<<g4, b, 0, stream>>>(nbr1, nbr2, xnh1, xnh2, agh1, agh2, h1, h2,
                                       watt, qq1, qq2, slo1, slo2, shi1, shi2, flag);
    attn_kernel <<<ga, b, 0, stream>>>(nbr1, nbr2, (const unsigned short*)agh1,
                                       (const unsigned short*)agh2, qq1, qq2,
                                       slo1, slo2, shi1, shi2, nm1, nm2);
    lin2_kernel <<<gl, b, 0, stream>>>(h1, h2, We2, Ws2, wtg, xnh1, xnh2, d_out, flag);
    aggr2_kernel<<<g4, b, 0, stream>>>(nbr1, nbr2, xnh1, xnh2, nm1, nm2, d_out, flag);
}

// Round 5
// 261.742 us; speedup vs baseline: 2.8419x; 1.3574x over previous
//
#include <hip/hip_runtime.h>
#include <hip/hip_bf16.h>

#define N_NODES 50000
#define K_NBR   16
#define DIN     128
#define DOUT    64
#define NPB     64   // nodes per block in the linear kernels

typedef __hip_bfloat16 bf16;
typedef __attribute__((ext_vector_type(8))) short bf16x8;
typedef __attribute__((ext_vector_type(4))) float f32x4;

__device__ __forceinline__ float b2f(bf16 v) { return __bfloat162float(v); }
__device__ __forceinline__ float sigmoidf_(float x) { return 1.0f / (1.0f + __expf(-x)); }
__device__ __forceinline__ short f2bs(float f) {
    bf16 b = __float2bfloat16(f);
    return *reinterpret_cast<short*>(&b);
}

template <typename T> __device__ __forceinline__ float ld(const T* p, size_t i);
template <> __device__ __forceinline__ float ld<float>(const float* p, size_t i) { return p[i]; }
template <> __device__ __forceinline__ float ld<bf16>(const bf16* p, size_t i)   { return b2f(p[i]); }

template <typename T> __device__ __forceinline__ void st(T* p, size_t i, float v);
template <> __device__ __forceinline__ void st<float>(float* p, size_t i, float v) { p[i] = v; }
template <> __device__ __forceinline__ void st<bf16>(bf16* p, size_t i, float v)   { p[i] = __float2bfloat16(v); }

// A-fragment loaders: 8 k-contiguous bf16 values from a global row.
__device__ __forceinline__ bf16x8 load_a8(const bf16* p) { return *(const bf16x8*)p; }
__device__ __forceinline__ bf16x8 load_a8(const float* p) {
    float4 v0 = *(const float4*)p;
    float4 v1 = *(const float4*)(p + 4);
    bf16x8 r;
    r[0] = f2bs(v0.x); r[1] = f2bs(v0.y); r[2] = f2bs(v0.z); r[3] = f2bs(v0.w);
    r[4] = f2bs(v1.x); r[5] = f2bs(v1.y); r[6] = f2bs(v1.z); r[7] = f2bs(v1.w);
    return r;
}

// ---------------------------------------------------------------------------
// Dtype detector. flag: 1 = float32 data, 0 = bf16 data.
// (Round-4 counters: lin1 bank-conflicts == f32-path signature -> data IS f32;
//  the round-3 FETCH-based bf16 inference was L3-absorption masking.)
// ---------------------------------------------------------------------------
__global__ void detect_kernel(const unsigned short* __restrict__ x, int* __restrict__ flag)
{
    __shared__ int cnt;
    if (threadIdx.x == 0) cnt = 0;
    __syncthreads();
    int c = 0;
#pragma unroll
    for (int i = 0; i < 16; ++i) {
        unsigned short w = x[(size_t)(threadIdx.x * 16 + i) * 2];  // low half-word
        int e = (w >> 7) & 0xFF;
        c += (e >= 112 && e <= 142) ? 1 : 0;
    }
    atomicAdd(&cnt, c);
    __syncthreads();
    if (threadIdx.x == 0) *flag = (cnt >= 2048) ? 0 : 1;
}

// ---------------------------------------------------------------------------
// Weight transpose + bf16-convert pre-kernel: wtg[mat][d][k] (bf16, 64x128)
// from W[mat][k][d] (f32 or bf16 per flag). One block per mat.
// ---------------------------------------------------------------------------
__global__ __launch_bounds__(256) void wtrans_kernel(
    const void* __restrict__ Wa, const void* __restrict__ Wb,
    const void* __restrict__ Wc, const void* __restrict__ Wd,
    unsigned short* __restrict__ wtg, const int* __restrict__ flag)
{
    __shared__ unsigned short t[DIN][DOUT + 1];
    const void* W = (blockIdx.x == 0 ? Wa : blockIdx.x == 1 ? Wb : blockIdx.x == 2 ? Wc : Wd);
    unsigned short* o = wtg + (size_t)blockIdx.x * DIN * DOUT;
    if (*flag) {
        const float* Wf = (const float*)W;
#pragma unroll 8
        for (int it = 0; it < 32; ++it) {
            int idx = threadIdx.x + 256 * it;           // 8192 elems
            t[idx >> 6][idx & 63] = (unsigned short)f2bs(Wf[idx]);
        }
    } else {
        const unsigned short* Wh = (const unsigned short*)W;
#pragma unroll 8
        for (int it = 0; it < 32; ++it) {
            int idx = threadIdx.x + 256 * it;
            t[idx >> 6][idx & 63] = Wh[idx];
        }
    }
    __syncthreads();
#pragma unroll 8
    for (int it = 0; it < 32; ++it) {
        int idx = threadIdx.x + 256 * it;
        int d = idx >> 7, k = idx & 127;
        o[idx] = t[k][d];                           // coalesced write
    }
}

// ---------------------------------------------------------------------------
// MFMA dual linear: xnh = bf16(x @ We), o[:, :64] = sigmoid(x @ Ws).
// Block tile 64 nodes x 64 d, K=128. ONLY the two 8KB weight tiles live in
// LDS (XOR slot swizzle -> b128 reads at return-BW floor). A-fragments load
// straight from global: each x-row is consumed exclusively by one wave
// (lane(m,g): row w*16+m, k-chunk ks*32+g*8), so rows are fetched once and
// LDS staging of x would be pure overhead. f32 inputs convert in-register.
// D layout (validated on HW by round-4 attn MFMA): col = lane&15,
// row = (lane>>4)*4 + reg.
// ---------------------------------------------------------------------------
template <typename TX, typename TO>
__device__ __forceinline__ void lin_mfma_body(
    const TX* __restrict__ x,                 // [N][128] rows
    const unsigned short* __restrict__ wt2,   // 2 mats of transposed W [d][k], bf16
    bf16* __restrict__ xnh, TO* __restrict__ o,
    unsigned short* __restrict__ wt)          // LDS, 2*64*128 ushorts
{
    const int tid = threadIdx.x;
    const int nbase = blockIdx.x * NPB;

    // stage both weight mats, 16B chunks, slot-swizzled (chunk c of row r -> c^(r&15))
#pragma unroll
    for (int it = 0; it < 8; ++it) {
        int idx = tid + 256 * it;               // 0..2047
        int mt = idx >> 10, rem = idx & 1023;
        int r = rem >> 4, c = rem & 15;
        int4 v = *(const int4*)(wt2 + mt * 8192 + r * DIN + c * 8);
        *(int4*)(wt + mt * 8192 + r * DIN + ((c ^ (r & 15)) << 3)) = v;
    }
    __syncthreads();

    const int w = tid >> 6, lane = tid & 63;
    const int m = lane & 15, g = lane >> 4;

    int arow = nbase + w * 16 + m;
    if (arow >= N_NODES) arow = N_NODES - 1;    // tail: duplicate reads, writes guarded
    const TX* xrow = x + (size_t)arow * DIN;

    f32x4 acc[2][4] = {};
#pragma unroll
    for (int ks = 0; ks < 4; ++ks) {
        bf16x8 a = load_a8(xrow + ks * 32 + g * 8);
        int slot = ((ks * 4 + g) ^ m) << 3;     // 8-ushort slot offset
#pragma unroll
        for (int mt = 0; mt < 2; ++mt)
#pragma unroll
        for (int nc = 0; nc < 4; ++nc) {
            bf16x8 b = *(const bf16x8*)(wt + mt * 8192 + (nc * 16 + m) * DIN + slot);
            acc[mt][nc] = __builtin_amdgcn_mfma_f32_16x16x32_bf16(a, b, acc[mt][nc], 0, 0, 0);
        }
    }

#pragma unroll
    for (int nc = 0; nc < 4; ++nc) {
#pragma unroll
        for (int j = 0; j < 4; ++j) {
            int n = nbase + w * 16 + g * 4 + j;
            if (n < N_NODES) {
                int d = nc * 16 + m;
                xnh[(size_t)n * DOUT + d] = __float2bfloat16(acc[0][nc][j]);
                st(o, (size_t)n * DIN + d, sigmoidf_(acc[1][nc][j]));
            }
        }
    }
}

__global__ __launch_bounds__(256) void lin1_kernel(
    const void* __restrict__ x1, const void* __restrict__ x2,
    const unsigned short* __restrict__ wtg,
    bf16* __restrict__ xnh1, bf16* __restrict__ xnh2,
    bf16* __restrict__ h1, bf16* __restrict__ h2,
    const int* __restrict__ flag)
{
    __shared__ __align__(16) unsigned short wt[2 * DOUT * DIN];   // 32 KB
    const int g = blockIdx.y;
    const void* x   = g ? x2 : x1;
    bf16*       xnh = g ? xnh2 : xnh1;
    bf16*       h   = g ? h2 : h1;
    if (*flag) lin_mfma_body<float, bf16>((const float*)x, wtg, xnh, h, wt);
    else       lin_mfma_body<bf16,  bf16>((const bf16*)x,  wtg, xnh, h, wt);
}

__global__ __launch_bounds__(256) void lin2_kernel(
    const bf16* __restrict__ h1, const bf16* __restrict__ h2,
    const unsigned short* __restrict__ wtg,
    bf16* __restrict__ heh1, bf16* __restrict__ heh2,
    void* __restrict__ out, const int* __restrict__ flag)
{
    __shared__ __align__(16) unsigned short wt[2 * DOUT * DIN];   // 32 KB
    const int g = blockIdx.y;
    const bf16* h   = g ? h2 : h1;
    bf16*       heh = g ? heh2 : heh1;
    if (*flag) lin_mfma_body<bf16, float>(h, wtg + 2 * 8192, heh,
                                          (float*)out + (size_t)g * N_NODES * DIN, wt);
    else       lin_mfma_body<bf16, bf16>(h, wtg + 2 * 8192, heh,
                                         (bf16*)out + (size_t)g * N_NODES * DIN, wt);
}

// ---------------------------------------------------------------------------
// Pass B: aggr = (1/K) sum_k xnh[nbr[n,k]] (bf16 gather, f32 accumulate).
// Writes agh = bf16(aggr) + h[:, 64:] = sigmoid(aggr) + per-node scalars
// qq (from the ROUNDED aggregate, so attn's d2 = |a1-a2|^2 >= 0 exactly),
// slo/shi (self-attn terms).
// ---------------------------------------------------------------------------
template <typename T>
__device__ __forceinline__ void aggr1_body(
    const int* __restrict__ nbr, const bf16* __restrict__ xnh,
    bf16* __restrict__ agh, bf16* __restrict__ h, const T* __restrict__ watt,
    float* __restrict__ qq, float* __restrict__ slo, float* __restrict__ shi)
{
    const int warp = threadIdx.x >> 6;
    const int lane = threadIdx.x & 63;
    const int n = blockIdx.x * 4 + warp;

    int idx_l = nbr[n * K_NBR + (lane & 15)];
    float acc = 0.f;
#pragma unroll
    for (int k = 0; k < K_NBR; ++k) {
        int idx = __shfl(idx_l, k, 64);
        acc += b2f(xnh[(size_t)idx * DOUT + lane]);
    }
    acc *= (1.0f / K_NBR);
    bf16 av16 = __float2bfloat16(acc);
    float av = b2f(av16);
    agh[(size_t)n * DOUT + lane] = av16;
    h[(size_t)n * DIN + DOUT + lane] = __float2bfloat16(sigmoidf_(acc));

    float wl = ld(watt, lane);
    float wh = ld(watt, DOUT + lane);
    float pq = av * av;
    float pl = acc * wl;
    float ph = acc * wh;
#pragma unroll
    for (int off = 1; off < 64; off <<= 1) {
        pq += __shfl_xor(pq, off, 64);
        pl += __shfl_xor(pl, off, 64);
        ph += __shfl_xor(ph, off, 64);
    }
    if (lane == 0) { qq[n] = pq; slo[n] = pl; shi[n] = ph; }
}

__global__ __launch_bounds__(256) void aggr1_kernel(
    const int* __restrict__ nbr1, const int* __restrict__ nbr2,
    const bf16* __restrict__ xnh1, const bf16* __restrict__ xnh2,
    bf16* __restrict__ agh1, bf16* __restrict__ agh2,
    bf16* __restrict__ h1, bf16* __restrict__ h2,
    const void* __restrict__ watt,
    float* __restrict__ qq1, float* __restrict__ qq2,
    float* __restrict__ slo1, float* __restrict__ slo2,
    float* __restrict__ shi1, float* __restrict__ shi2,
    const int* __restrict__ flag)
{
    const int g = blockIdx.y;
    const int*  nbr = g ? nbr2 : nbr1;
    const bf16* xnh = g ? xnh2 : xnh1;
    bf16*       agh = g ? agh2 : agh1;
    bf16*       h   = g ? h2 : h1;
    float* qq  = g ? qq2  : qq1;
    float* slo = g ? slo2 : slo1;
    float* shi = g ? shi2 : shi1;
    if (*flag) aggr1_body<float>(nbr, xnh, agh, h, (const float*)watt, qq, slo, shi);
    else       aggr1_body<bf16>(nbr, xnh, agh, h, (const bf16*)watt,  qq, slo, shi);
}

// ---------------------------------------------------------------------------
// Pass C: fused self-attn + cross-attn -> norm1/norm2 [N,K] (f32).
// One wave per node, ZERO LDS; 16x16 dot matrix = 2 MFMAs with fragments
// gathered straight from global bf16 agh rows. (Validated round 4.)
// ---------------------------------------------------------------------------
__global__ __launch_bounds__(256) void attn_kernel(
    const int* __restrict__ nbr1, const int* __restrict__ nbr2,
    const unsigned short* __restrict__ agh1, const unsigned short* __restrict__ agh2,
    const float* __restrict__ qq1, const float* __restrict__ qq2,
    const float* __restrict__ slo1, const float* __restrict__ slo2,
    const float* __restrict__ shi1, const float* __restrict__ shi2,
    float* __restrict__ norm1, float* __restrict__ norm2)
{
    const int warp = threadIdx.x >> 6;
    const int lane = threadIdx.x & 63;
    const int n = blockIdx.x * 4 + warp;
    const int m = lane & 15, g = lane >> 4;

    int idxr = 0;
    if (lane < 32) idxr = ((lane < 16) ? nbr1 : nbr2)[n * K_NBR + m];

    const int i1 = __shfl(idxr, m, 64);
    const int i2 = __shfl(idxr, 16 + m, 64);

    const bf16x8* a1p = (const bf16x8*)(agh1 + (size_t)i1 * DOUT + g * 8);
    const bf16x8* a2p = (const bf16x8*)(agh2 + (size_t)i2 * DOUT + g * 8);
    bf16x8 aA = a1p[0], aB = a1p[4];   // dims 0..31, 32..63 (row i1)
    bf16x8 bA = a2p[0], bB = a2p[4];   // dims 0..31, 32..63 (row i2)

    int myidx = __shfl(idxr, lane & 31, 64);
    const float* pa = (lane < 16) ? qq1 : (lane < 32) ? qq2 : (lane < 48) ? shi1 : shi2;
    float aux = pa[(size_t)myidx];

    float si  = (lane < 16) ? slo1[n] : slo2[n];
    float sjv = __shfl(aux, 32 + (lane & 31), 64);
    float v = si + sjv;
    v = v > 0.f ? v : 0.01f * v;
    float ev = __expf(v);
    float esum = ev;
#pragma unroll
    for (int off = 1; off < 16; off <<= 1) esum += __shfl_xor(esum, off, 64);

    f32x4 acc = {};
    acc = __builtin_amdgcn_mfma_f32_16x16x32_bf16(aA, bA, acc, 0, 0, 0);
    acc = __builtin_amdgcn_mfma_f32_16x16x32_bf16(aB, bB, acc, 0, 0, 0);

    float q2c = __shfl(aux, 16 + m, 64);
    float s0, s1, s2, s3;
    {
        float q10 = __shfl(aux, g * 4 + 0, 64);
        float q11 = __shfl(aux, g * 4 + 1, 64);
        float q12 = __shfl(aux, g * 4 + 2, 64);
        float q13 = __shfl(aux, g * 4 + 3, 64);
        s0 = __expf(-sqrtf(fmaxf(q10 + q2c - 2.f * acc[0], 1e-12f)));
        s1 = __expf(-sqrtf(fmaxf(q11 + q2c - 2.f * acc[1], 1e-12f)));
        s2 = __expf(-sqrtf(fmaxf(q12 + q2c - 2.f * acc[2], 1e-12f)));
        s3 = __expf(-sqrtf(fmaxf(q13 + q2c - 2.f * acc[3], 1e-12f)));
    }

    float c = s0 + s1 + s2 + s3;
#pragma unroll
    for (int off = 1; off < 16; off <<= 1) {
        s0 += __shfl_xor(s0, off, 64);
        s1 += __shfl_xor(s1, off, 64);
        s2 += __shfl_xor(s2, off, 64);
        s3 += __shfl_xor(s3, off, 64);
    }
    float cs = c;
    cs += __shfl_xor(cs, 16, 64);
    cs += __shfl_xor(cs, 32, 64);
    float tot = cs;
#pragma unroll
    for (int off = 1; off < 16; off <<= 1) tot += __shfl_xor(tot, off, 64);
    float rt = 1.0f / tot;

    if (g == 1) norm2[(size_t)n * K_NBR + m] = cs * rt * ev / esum;

    float r0 = __shfl(s0, (m >> 2) << 4, 64);
    float r1 = __shfl(s1, (m >> 2) << 4, 64);
    float r2 = __shfl(s2, (m >> 2) << 4, 64);
    float r3 = __shfl(s3, (m >> 2) << 4, 64);
    int mr = m & 3;
    float rsm = mr == 0 ? r0 : mr == 1 ? r1 : mr == 2 ? r2 : r3;
    if (g == 0) norm1[(size_t)n * K_NBR + m] = rsm * rt * ev / esum;
}

// ---------------------------------------------------------------------------
// Pass E: out[:, 64:] = sigmoid(sum_k norm[n,k] * heh[nbr[n,k]]) (bf16 gather)
// ---------------------------------------------------------------------------
template <typename T>
__device__ __forceinline__ void aggr2_body(
    const int* __restrict__ nbr, const bf16* __restrict__ heh,
    const float* __restrict__ nm, T* __restrict__ o)
{
    const int warp = threadIdx.x >> 6;
    const int lane = threadIdx.x & 63;
    const int n = blockIdx.x * 4 + warp;

    int   idx_l = nbr[n * K_NBR + (lane & 15)];
    float w_l   = nm[n * K_NBR + (lane & 15)];
    float acc = 0.f;
#pragma unroll
    for (int k = 0; k < K_NBR; ++k) {
        int   idx = __shfl(idx_l, k, 64);
        float w   = __shfl(w_l, k, 64);
        acc += w * b2f(heh[(size_t)idx * DOUT + lane]);
    }
    st(o, (size_t)n * DIN + DOUT + lane, sigmoidf_(acc));
}

__global__ __launch_bounds__(256) void aggr2_kernel(
    const int* __restrict__ nbr1, const int* __restrict__ nbr2,
    const bf16* __restrict__ heh1, const bf16* __restrict__ heh2,
    const float* __restrict__ nm1, const float* __restrict__ nm2,
    void* __restrict__ out, const int* __restrict__ flag)
{
    const int g = blockIdx.y;
    const int*  nbr = g ? nbr2 : nbr1;
    const bf16* heh = g ? heh2 : heh1;
    const float* nm = g ? nm2 : nm1;
    if (*flag) aggr2_body<float>(nbr, heh, nm, (float*)out + (size_t)g * N_NODES * DIN);
    else       aggr2_body<bf16>(nbr, heh, nm, (bf16*)out + (size_t)g * N_NODES * DIN);
}

// ---------------------------------------------------------------------------
extern "C" void kernel_launch(void* const* d_in, const int* in_sizes, int n_in,
                              void* d_out, int out_size, void* d_ws, size_t ws_size,
                              hipStream_t stream)
{
    const void* x1   = d_in[0];
    const void* x2   = d_in[1];
    const int*  nbr1 = (const int*)d_in[2];
    const int*  nbr2 = (const int*)d_in[3];
    const void* We1  = d_in[4];
    const void* Ws1  = d_in[5];
    const void* We2  = d_in[6];
    const void* Ws2  = d_in[7];
    const void* watt = d_in[8];

    char* ws = (char*)d_ws;
    const size_t SZH  = (size_t)N_NODES * DOUT * sizeof(bf16);   // 6.4 MB
    const size_t HSZ  = (size_t)N_NODES * DIN * sizeof(bf16);    // 12.8 MB
    const size_t NMSZ = (size_t)N_NODES * K_NBR * sizeof(float); //  3.2 MB
    const size_t NSZ  = (size_t)N_NODES * sizeof(float);         //  0.2 MB
    bf16* xnh1 = (bf16*)(ws + 0 * SZH);   // later reused as heh1
    bf16* xnh2 = (bf16*)(ws + 1 * SZH);   // later reused as heh2
    bf16* agh1 = (bf16*)(ws + 2 * SZH);
    bf16* agh2 = (bf16*)(ws + 3 * SZH);
    bf16* h1   = (bf16*)(ws + 4 * SZH);
    bf16* h2   = (bf16*)(ws + 4 * SZH + HSZ);
    char* p    =         ws + 4 * SZH + 2 * HSZ;
    float* nm1 = (float*)(p);
    float* nm2 = (float*)(p + NMSZ);
    int*  flag = (int*)  (p + 2 * NMSZ);
    char* aux  =          p + 2 * NMSZ + 4096;
    float* qq1  = (float*)(aux + 0 * NSZ);
    float* qq2  = (float*)(aux + 1 * NSZ);
    float* slo1 = (float*)(aux + 2 * NSZ);
    float* slo2 = (float*)(aux + 3 * NSZ);
    float* shi1 = (float*)(aux + 4 * NSZ);
    float* shi2 = (float*)(aux + 5 * NSZ);
    unsigned short* wtg = (unsigned short*)(aux + 6 * NSZ);  // 4 x 16KB transposed bf16 W

    dim3 b(256);
    dim3 g4(N_NODES / 4, 2);                       // gather kernels: 1 wave/node
    dim3 gl((N_NODES + NPB - 1) / NPB, 2);         // linear kernels: 64 nodes/block
    dim3 ga(N_NODES / 4);                          // attn: 4 node-waves/block

    detect_kernel<<<dim3(1), b, 0, stream>>>((const unsigned short*)x1, flag);
    wtrans_kernel<<<dim3(4), b, 0, stream>>>(We1, Ws1, We2, Ws2, wtg, flag);
    lin1_kernel <<<gl, b, 0, stream>>>(x1, x2, wtg, xnh1, xnh2, h1, h2, flag);
    aggr1_kernel<<<g4, b, 0, stream>>>(nbr1, nbr2, xnh1, xnh2, agh1, agh2, h1, h2,
                                       watt, qq1, qq2, slo1, slo2, shi1, shi2, flag);
    attn_kernel <<<ga, b, 0, stream>>>(nbr1, nbr2, (const unsigned short*)agh1,
                                       (const unsigned short*)agh2, qq1, qq2,
                                       slo1, slo2, shi1, shi2, nm1, nm2);
    lin2_kernel <<<gl, b, 0, stream>>>(h1, h2, wtg, xnh1, xnh2, d_out, flag);
    aggr2_kernel<<<g4, b, 0, stream>>>(nbr1, nbr2, xnh1, xnh2, nm1, nm2, d_out, flag);
}

// Round 6
// 238.485 us; speedup vs baseline: 3.1190x; 1.0975x over previous
//
#include <hip/hip_runtime.h>
#include <hip/hip_bf16.h>

#define N_NODES 50000
#define K_NBR   16
#define DIN     128
#define DOUT    64
#define NPB     64   // nodes per block in the linear kernels

typedef __hip_bfloat16 bf16;
typedef __attribute__((ext_vector_type(8))) short bf16x8;
typedef __attribute__((ext_vector_type(4))) float f32x4;

__device__ __forceinline__ float b2f(bf16 v) { return __bfloat162float(v); }
__device__ __forceinline__ float sigmoidf_(float x) { return 1.0f / (1.0f + __expf(-x)); }
__device__ __forceinline__ short f2bs(float f) {
    bf16 b = __float2bfloat16(f);
    return *reinterpret_cast<short*>(&b);
}

template <typename T> __device__ __forceinline__ float ld(const T* p, size_t i);
template <> __device__ __forceinline__ float ld<float>(const float* p, size_t i) { return p[i]; }
template <> __device__ __forceinline__ float ld<bf16>(const bf16* p, size_t i)   { return b2f(p[i]); }

template <typename T> __device__ __forceinline__ void st(T* p, size_t i, float v);
template <> __device__ __forceinline__ void st<float>(float* p, size_t i, float v) { p[i] = v; }
template <> __device__ __forceinline__ void st<bf16>(bf16* p, size_t i, float v)   { p[i] = __float2bfloat16(v); }

// A-fragment loaders: 8 k-contiguous bf16 values from a global row.
__device__ __forceinline__ bf16x8 load_a8(const bf16* p) { return *(const bf16x8*)p; }
__device__ __forceinline__ bf16x8 load_a8(const float* p) {
    float4 v0 = *(const float4*)p;
    float4 v1 = *(const float4*)(p + 4);
    bf16x8 r;
    r[0] = f2bs(v0.x); r[1] = f2bs(v0.y); r[2] = f2bs(v0.z); r[3] = f2bs(v0.w);
    r[4] = f2bs(v1.x); r[5] = f2bs(v1.y); r[6] = f2bs(v1.z); r[7] = f2bs(v1.w);
    return r;
}

// ---------------------------------------------------------------------------
// Weight transpose + dtype-detect (fused; saves a serialized launch).
// Each block self-detects f32-vs-bf16 from the first 16KB of x1 (low
// half-words of a true-bf16 array are sane gaussian exponents; of an f32
// array they're mantissa garbage). Block 0 publishes the flag for the
// downstream kernels. Then: wtg[mat][d][k] (bf16, 64x128) from W[mat][k][d].
// flag: 1 = float32 data, 0 = bf16 data.
// ---------------------------------------------------------------------------
__global__ __launch_bounds__(256) void wtrans_kernel(
    const void* __restrict__ Wa, const void* __restrict__ Wb,
    const void* __restrict__ Wc, const void* __restrict__ Wd,
    const unsigned short* __restrict__ x1probe,
    unsigned short* __restrict__ wtg, int* __restrict__ flag)
{
    __shared__ unsigned short t[DIN][DOUT + 1];
    __shared__ int cnt;
    if (threadIdx.x == 0) cnt = 0;
    __syncthreads();
    int c = 0;
#pragma unroll
    for (int i = 0; i < 16; ++i) {
        unsigned short w = x1probe[(size_t)(threadIdx.x * 16 + i) * 2];  // low half-word
        int e = (w >> 7) & 0xFF;
        c += (e >= 112 && e <= 142) ? 1 : 0;
    }
    atomicAdd(&cnt, c);
    __syncthreads();
    const int isf32 = (cnt >= 2048) ? 0 : 1;
    if (blockIdx.x == 0 && threadIdx.x == 0) *flag = isf32;

    const void* W = (blockIdx.x == 0 ? Wa : blockIdx.x == 1 ? Wb : blockIdx.x == 2 ? Wc : Wd);
    unsigned short* o = wtg + (size_t)blockIdx.x * DIN * DOUT;
    if (isf32) {
        const float* Wf = (const float*)W;
#pragma unroll 8
        for (int it = 0; it < 32; ++it) {
            int idx = threadIdx.x + 256 * it;           // 8192 elems
            t[idx >> 6][idx & 63] = (unsigned short)f2bs(Wf[idx]);
        }
    } else {
        const unsigned short* Wh = (const unsigned short*)W;
#pragma unroll 8
        for (int it = 0; it < 32; ++it) {
            int idx = threadIdx.x + 256 * it;
            t[idx >> 6][idx & 63] = Wh[idx];
        }
    }
    __syncthreads();
#pragma unroll 8
    for (int it = 0; it < 32; ++it) {
        int idx = threadIdx.x + 256 * it;
        int d = idx >> 7, k = idx & 127;
        o[idx] = t[k][d];                           // coalesced write
    }
}

// ---------------------------------------------------------------------------
// MFMA dual linear: xnh = bf16(x @ We), o[:, :64] = sigmoid(x @ Ws).
// Block tile 64 nodes x 64 d, K=128. Only the two 8KB weight tiles in LDS
// (XOR slot swizzle). A-fragments load straight from global (each x-row
// consumed exclusively by one wave). Validated rounds 4-5.
// ---------------------------------------------------------------------------
template <typename TX, typename TO>
__device__ __forceinline__ void lin_mfma_body(
    const TX* __restrict__ x,                 // [N][128] rows
    const unsigned short* __restrict__ wt2,   // 2 mats of transposed W [d][k], bf16
    bf16* __restrict__ xnh, TO* __restrict__ o,
    unsigned short* __restrict__ wt)          // LDS, 2*64*128 ushorts
{
    const int tid = threadIdx.x;
    const int nbase = blockIdx.x * NPB;

#pragma unroll
    for (int it = 0; it < 8; ++it) {
        int idx = tid + 256 * it;               // 0..2047
        int mt = idx >> 10, rem = idx & 1023;
        int r = rem >> 4, c = rem & 15;
        int4 v = *(const int4*)(wt2 + mt * 8192 + r * DIN + c * 8);
        *(int4*)(wt + mt * 8192 + r * DIN + ((c ^ (r & 15)) << 3)) = v;
    }
    __syncthreads();

    const int w = tid >> 6, lane = tid & 63;
    const int m = lane & 15, g = lane >> 4;

    int arow = nbase + w * 16 + m;
    if (arow >= N_NODES) arow = N_NODES - 1;    // tail: duplicate reads, writes guarded
    const TX* xrow = x + (size_t)arow * DIN;

    f32x4 acc[2][4] = {};
#pragma unroll
    for (int ks = 0; ks < 4; ++ks) {
        bf16x8 a = load_a8(xrow + ks * 32 + g * 8);
        int slot = ((ks * 4 + g) ^ m) << 3;     // 8-ushort slot offset
#pragma unroll
        for (int mt = 0; mt < 2; ++mt)
#pragma unroll
        for (int nc = 0; nc < 4; ++nc) {
            bf16x8 b = *(const bf16x8*)(wt + mt * 8192 + (nc * 16 + m) * DIN + slot);
            acc[mt][nc] = __builtin_amdgcn_mfma_f32_16x16x32_bf16(a, b, acc[mt][nc], 0, 0, 0);
        }
    }

#pragma unroll
    for (int nc = 0; nc < 4; ++nc) {
#pragma unroll
        for (int j = 0; j < 4; ++j) {
            int n = nbase + w * 16 + g * 4 + j;
            if (n < N_NODES) {
                int d = nc * 16 + m;
                xnh[(size_t)n * DOUT + d] = __float2bfloat16(acc[0][nc][j]);
                st(o, (size_t)n * DIN + d, sigmoidf_(acc[1][nc][j]));
            }
        }
    }
}

__global__ __launch_bounds__(256) void lin1_kernel(
    const void* __restrict__ x1, const void* __restrict__ x2,
    const unsigned short* __restrict__ wtg,
    bf16* __restrict__ xnh1, bf16* __restrict__ xnh2,
    bf16* __restrict__ h1, bf16* __restrict__ h2,
    const int* __restrict__ flag)
{
    __shared__ __align__(16) unsigned short wt[2 * DOUT * DIN];   // 32 KB
    const int g = blockIdx.y;
    const void* x   = g ? x2 : x1;
    bf16*       xnh = g ? xnh2 : xnh1;
    bf16*       h   = g ? h2 : h1;
    if (*flag) lin_mfma_body<float, bf16>((const float*)x, wtg, xnh, h, wt);
    else       lin_mfma_body<bf16,  bf16>((const bf16*)x,  wtg, xnh, h, wt);
}

__global__ __launch_bounds__(256) void lin2_kernel(
    const bf16* __restrict__ h1, const bf16* __restrict__ h2,
    const unsigned short* __restrict__ wtg,
    bf16* __restrict__ heh1, bf16* __restrict__ heh2,
    void* __restrict__ out, const int* __restrict__ flag)
{
    __shared__ __align__(16) unsigned short wt[2 * DOUT * DIN];   // 32 KB
    const int g = blockIdx.y;
    const bf16* h   = g ? h2 : h1;
    bf16*       heh = g ? heh2 : heh1;
    if (*flag) lin_mfma_body<bf16, float>(h, wtg + 2 * 8192, heh,
                                          (float*)out + (size_t)g * N_NODES * DIN, wt);
    else       lin_mfma_body<bf16, bf16>(h, wtg + 2 * 8192, heh,
                                         (bf16*)out + (size_t)g * N_NODES * DIN, wt);
}

// ---------------------------------------------------------------------------
// Pass B: aggr = (1/K) sum_k xnh[nbr[n,k]] (bf16 gather, f32 accumulate).
// SGPR-uniform indexing: n is readfirstlane-uniform, so nbr row loads become
// s_load and every gather is saddr + (lane*2) voffset -- zero per-load VALU
// (was 16 shfl + ~48 addr VALU per wave; aggr1 was VALU/latency-bound at
// 46us vs a 14us BW floor). Arithmetic identical to round 5.
// ---------------------------------------------------------------------------
template <typename T>
__device__ __forceinline__ void aggr1_body(
    const int* __restrict__ nbr, const bf16* __restrict__ xnh,
    bf16* __restrict__ agh, bf16* __restrict__ h, const T* __restrict__ watt,
    float* __restrict__ qq, float* __restrict__ slo, float* __restrict__ shi)
{
    const int warp = __builtin_amdgcn_readfirstlane(threadIdx.x >> 6);
    const int lane = threadIdx.x & 63;
    const int n = blockIdx.x * 4 + warp;
    const int* __restrict__ nrow = nbr + n * K_NBR;

    float acc = 0.f;
#pragma unroll
    for (int k = 0; k < K_NBR; ++k) {
        int idx = nrow[k];                            // uniform -> s_load
        acc += b2f(xnh[(size_t)idx * DOUT + lane]);   // saddr gather, 0 addr VALU
    }
    acc *= (1.0f / K_NBR);
    bf16 av16 = __float2bfloat16(acc);
    float av = b2f(av16);
    agh[(size_t)n * DOUT + lane] = av16;
    h[(size_t)n * DIN + DOUT + lane] = __float2bfloat16(sigmoidf_(acc));

    float wl = ld(watt, lane);
    float wh = ld(watt, DOUT + lane);
    float pq = av * av;
    float pl = acc * wl;
    float ph = acc * wh;
#pragma unroll
    for (int off = 1; off < 64; off <<= 1) {
        pq += __shfl_xor(pq, off, 64);
        pl += __shfl_xor(pl, off, 64);
        ph += __shfl_xor(ph, off, 64);
    }
    if (lane == 0) { qq[n] = pq; slo[n] = pl; shi[n] = ph; }
}

__global__ __launch_bounds__(256) void aggr1_kernel(
    const int* __restrict__ nbr1, const int* __restrict__ nbr2,
    const bf16* __restrict__ xnh1, const bf16* __restrict__ xnh2,
    bf16* __restrict__ agh1, bf16* __restrict__ agh2,
    bf16* __restrict__ h1, bf16* __restrict__ h2,
    const void* __restrict__ watt,
    float* __restrict__ qq1, float* __restrict__ qq2,
    float* __restrict__ slo1, float* __restrict__ slo2,
    float* __restrict__ shi1, float* __restrict__ shi2,
    const int* __restrict__ flag)
{
    const int g = blockIdx.y;
    const int*  nbr = g ? nbr2 : nbr1;
    const bf16* xnh = g ? xnh2 : xnh1;
    bf16*       agh = g ? agh2 : agh1;
    bf16*       h   = g ? h2 : h1;
    float* qq  = g ? qq2  : qq1;
    float* slo = g ? slo2 : slo1;
    float* shi = g ? shi2 : shi1;
    if (*flag) aggr1_body<float>(nbr, xnh, agh, h, (const float*)watt, qq, slo, shi);
    else       aggr1_body<bf16>(nbr, xnh, agh, h, (const bf16*)watt,  qq, slo, shi);
}

// ---------------------------------------------------------------------------
// Pass C: fused self-attn + cross-attn -> norm1/norm2 [N,K] (f32).
// One wave per node, ZERO LDS; 16x16 dot matrix = 2 MFMAs with fragments
// gathered straight from global bf16 agh rows. (Validated rounds 4-5.)
// ---------------------------------------------------------------------------
__global__ __launch_bounds__(256) void attn_kernel(
    const int* __restrict__ nbr1, const int* __restrict__ nbr2,
    const unsigned short* __restrict__ agh1, const unsigned short* __restrict__ agh2,
    const float* __restrict__ qq1, const float* __restrict__ qq2,
    const float* __restrict__ slo1, const float* __restrict__ slo2,
    const float* __restrict__ shi1, const float* __restrict__ shi2,
    float* __restrict__ norm1, float* __restrict__ norm2)
{
    const int warp = threadIdx.x >> 6;
    const int lane = threadIdx.x & 63;
    const int n = blockIdx.x * 4 + warp;
    const int m = lane & 15, g = lane >> 4;

    int idxr = 0;
    if (lane < 32) idxr = ((lane < 16) ? nbr1 : nbr2)[n * K_NBR + m];

    const int i1 = __shfl(idxr, m, 64);
    const int i2 = __shfl(idxr, 16 + m, 64);

    const bf16x8* a1p = (const bf16x8*)(agh1 + (size_t)i1 * DOUT + g * 8);
    const bf16x8* a2p = (const bf16x8*)(agh2 + (size_t)i2 * DOUT + g * 8);
    bf16x8 aA = a1p[0], aB = a1p[4];   // dims 0..31, 32..63 (row i1)
    bf16x8 bA = a2p[0], bB = a2p[4];   // dims 0..31, 32..63 (row i2)

    int myidx = __shfl(idxr, lane & 31, 64);
    const float* pa = (lane < 16) ? qq1 : (lane < 32) ? qq2 : (lane < 48) ? shi1 : shi2;
    float aux = pa[(size_t)myidx];

    float si  = (lane < 16) ? slo1[n] : slo2[n];
    float sjv = __shfl(aux, 32 + (lane & 31), 64);
    float v = si + sjv;
    v = v > 0.f ? v : 0.01f * v;
    float ev = __expf(v);
    float esum = ev;
#pragma unroll
    for (int off = 1; off < 16; off <<= 1) esum += __shfl_xor(esum, off, 64);

    f32x4 acc = {};
    acc = __builtin_amdgcn_mfma_f32_16x16x32_bf16(aA, bA, acc, 0, 0, 0);
    acc = __builtin_amdgcn_mfma_f32_16x16x32_bf16(aB, bB, acc, 0, 0, 0);

    float q2c = __shfl(aux, 16 + m, 64);
    float s0, s1, s2, s3;
    {
        float q10 = __shfl(aux, g * 4 + 0, 64);
        float q11 = __shfl(aux, g * 4 + 1, 64);
        float q12 = __shfl(aux, g * 4 + 2, 64);
        float q13 = __shfl(aux, g * 4 + 3, 64);
        s0 = __expf(-sqrtf(fmaxf(q10 + q2c - 2.f * acc[0], 1e-12f)));
        s1 = __expf(-sqrtf(fmaxf(q11 + q2c - 2.f * acc[1], 1e-12f)));
        s2 = __expf(-sqrtf(fmaxf(q12 + q2c - 2.f * acc[2], 1e-12f)));
        s3 = __expf(-sqrtf(fmaxf(q13 + q2c - 2.f * acc[3], 1e-12f)));
    }

    float c = s0 + s1 + s2 + s3;
#pragma unroll
    for (int off = 1; off < 16; off <<= 1) {
        s0 += __shfl_xor(s0, off, 64);
        s1 += __shfl_xor(s1, off, 64);
        s2 += __shfl_xor(s2, off, 64);
        s3 += __shfl_xor(s3, off, 64);
    }
    float cs = c;
    cs += __shfl_xor(cs, 16, 64);
    cs += __shfl_xor(cs, 32, 64);
    float tot = cs;
#pragma unroll
    for (int off = 1; off < 16; off <<= 1) tot += __shfl_xor(tot, off, 64);
    float rt = 1.0f / tot;

    if (g == 1) norm2[(size_t)n * K_NBR + m] = cs * rt * ev / esum;

    float r0 = __shfl(s0, (m >> 2) << 4, 64);
    float r1 = __shfl(s1, (m >> 2) << 4, 64);
    float r2 = __shfl(s2, (m >> 2) << 4, 64);
    float r3 = __shfl(s3, (m >> 2) << 4, 64);
    int mr = m & 3;
    float rsm = mr == 0 ? r0 : mr == 1 ? r1 : mr == 2 ? r2 : r3;
    if (g == 0) norm1[(size_t)n * K_NBR + m] = rsm * rt * ev / esum;
}

// ---------------------------------------------------------------------------
// Pass E: out[:, 64:] = sigmoid(sum_k norm[n,k] * heh[nbr[n,k]]).
// Same SGPR-uniform treatment: nbr row AND norm row are wave-uniform ->
// s_load; weight becomes an SGPR operand in the FMA.
// ---------------------------------------------------------------------------
template <typename T>
__device__ __forceinline__ void aggr2_body(
    const int* __restrict__ nbr, const bf16* __restrict__ heh,
    const float* __restrict__ nm, T* __restrict__ o)
{
    const int warp = __builtin_amdgcn_readfirstlane(threadIdx.x >> 6);
    const int lane = threadIdx.x & 63;
    const int n = blockIdx.x * 4 + warp;
    const int*   __restrict__ nrow = nbr + n * K_NBR;
    const float* __restrict__ wrow = nm + n * K_NBR;

    float acc = 0.f;
#pragma unroll
    for (int k = 0; k < K_NBR; ++k) {
        int   idx = nrow[k];                          // uniform -> s_load
        float w   = wrow[k];                          // uniform -> s_load
        acc += w * b2f(heh[(size_t)idx * DOUT + lane]);
    }
    st(o, (size_t)n * DIN + DOUT + lane, sigmoidf_(acc));
}

__global__ __launch_bounds__(256) void aggr2_kernel(
    const int* __restrict__ nbr1, const int* __restrict__ nbr2,
    const bf16* __restrict__ heh1, const bf16* __restrict__ heh2,
    const float* __restrict__ nm1, const float* __restrict__ nm2,
    void* __restrict__ out, const int* __restrict__ flag)
{
    const int g = blockIdx.y;
    const int*  nbr = g ? nbr2 : nbr1;
    const bf16* heh = g ? heh2 : heh1;
    const float* nm = g ? nm2 : nm1;
    if (*flag) aggr2_body<float>(nbr, heh, nm, (float*)out + (size_t)g * N_NODES * DIN);
    else       aggr2_body<bf16>(nbr, heh, nm, (bf16*)out + (size_t)g * N_NODES * DIN);
}

// ---------------------------------------------------------------------------
extern "C" void kernel_launch(void* const* d_in, const int* in_sizes, int n_in,
                              void* d_out, int out_size, void* d_ws, size_t ws_size,
                              hipStream_t stream)
{
    const void* x1   = d_in[0];
    const void* x2   = d_in[1];
    const int*  nbr1 = (const int*)d_in[2];
    const int*  nbr2 = (const int*)d_in[3];
    const void* We1  = d_in[4];
    const void* Ws1  = d_in[5];
    const void* We2  = d_in[6];
    const void* Ws2  = d_in[7];
    const void* watt = d_in[8];

    char* ws = (char*)d_ws;
    const size_t SZH  = (size_t)N_NODES * DOUT * sizeof(bf16);   // 6.4 MB
    const size_t HSZ  = (size_t)N_NODES * DIN * sizeof(bf16);    // 12.8 MB
    const size_t NMSZ = (size_t)N_NODES * K_NBR * sizeof(float); //  3.2 MB
    const size_t NSZ  = (size_t)N_NODES * sizeof(float);         //  0.2 MB
    bf16* xnh1 = (bf16*)(ws + 0 * SZH);   // later reused as heh1
    bf16* xnh2 = (bf16*)(ws + 1 * SZH);   // later reused as heh2
    bf16* agh1 = (bf16*)(ws + 2 * SZH);
    bf16* agh2 = (bf16*)(ws + 3 * SZH);
    bf16* h1   = (bf16*)(ws + 4 * SZH);
    bf16* h2   = (bf16*)(ws + 4 * SZH + HSZ);
    char* p    =         ws + 4 * SZH + 2 * HSZ;
    float* nm1 = (float*)(p);
    float* nm2 = (float*)(p + NMSZ);
    int*  flag = (int*)  (p + 2 * NMSZ);
    char* aux  =          p + 2 * NMSZ + 4096;
    float* qq1  = (float*)(aux + 0 * NSZ);
    float* qq2  = (float*)(aux + 1 * NSZ);
    float* slo1 = (float*)(aux + 2 * NSZ);
    float* slo2 = (float*)(aux + 3 * NSZ);
    float* shi1 = (float*)(aux + 4 * NSZ);
    float* shi2 = (float*)(aux + 5 * NSZ);
    unsigned short* wtg = (unsigned short*)(aux + 6 * NSZ);  // 4 x 16KB transposed bf16 W

    dim3 b(256);
    dim3 g4(N_NODES / 4, 2);                       // gather kernels: 1 wave/node
    dim3 gl((N_NODES + NPB - 1) / NPB, 2);         // linear kernels: 64 nodes/block
    dim3 ga(N_NODES / 4);                          // attn: 4 node-waves/block

    wtrans_kernel<<<dim3(4), b, 0, stream>>>(We1, Ws1, We2, Ws2,
                                             (const unsigned short*)x1, wtg, flag);
    lin1_kernel <<<gl, b, 0, stream>>>(x1, x2, wtg, xnh1, xnh2, h1, h2, flag);
    aggr1_kernel<<<g4, b, 0, stream>>>(nbr1, nbr2, xnh1, xnh2, agh1, agh2, h1, h2,
                                       watt, qq1, qq2, slo1, slo2, shi1, shi2, flag);
    attn_kernel <<<ga, b, 0, stream>>>(nbr1, nbr2, (const unsigned short*)agh1,
                                       (const unsigned short*)agh2, qq1, qq2,
                                       slo1, slo2, shi1, shi2, nm1, nm2);
    lin2_kernel <<<gl, b, 0, stream>>>(h1, h2, wtg, xnh1, xnh2, d_out, flag);
    aggr2_kernel<<<g4, b, 0, stream>>>(nbr1, nbr2, xnh1, xnh2, nm1, nm2, d_out, flag);
}

// Round 7
// 230.580 us; speedup vs baseline: 3.2260x; 1.0343x over previous
//
#include <hip/hip_runtime.h>
#include <hip/hip_bf16.h>

#define N_NODES 50000
#define K_NBR   16
#define DIN     128
#define DOUT    64
#define NPB     64   // nodes per block in the linear kernels

typedef __hip_bfloat16 bf16;
typedef __attribute__((ext_vector_type(8))) short bf16x8;
typedef __attribute__((ext_vector_type(4))) float f32x4;

__device__ __forceinline__ float b2f(bf16 v) { return __bfloat162float(v); }
__device__ __forceinline__ float sigmoidf_(float x) { return 1.0f / (1.0f + __expf(-x)); }
__device__ __forceinline__ short f2bs(float f) {
    bf16 b = __float2bfloat16(f);
    return *reinterpret_cast<short*>(&b);
}
// lane-constant broadcast without touching the DS pipe (attn is ds_bpermute-heavy:
// 400k SQ_LDS_BANK_CONFLICT with zero LDS in round 6)
__device__ __forceinline__ float readlane_f(float v, int lane) {
    return __uint_as_float(__builtin_amdgcn_readlane(__float_as_uint(v), lane));
}

template <typename T> __device__ __forceinline__ float ld(const T* p, size_t i);
template <> __device__ __forceinline__ float ld<float>(const float* p, size_t i) { return p[i]; }
template <> __device__ __forceinline__ float ld<bf16>(const bf16* p, size_t i)   { return b2f(p[i]); }

template <typename T> __device__ __forceinline__ void st(T* p, size_t i, float v);
template <> __device__ __forceinline__ void st<float>(float* p, size_t i, float v) { p[i] = v; }
template <> __device__ __forceinline__ void st<bf16>(bf16* p, size_t i, float v)   { p[i] = __float2bfloat16(v); }

// A-fragment loaders: 8 k-contiguous bf16 values from a global row.
__device__ __forceinline__ bf16x8 load_a8(const bf16* p) { return *(const bf16x8*)p; }
__device__ __forceinline__ bf16x8 load_a8(const float* p) {
    float4 v0 = *(const float4*)p;
    float4 v1 = *(const float4*)(p + 4);
    bf16x8 r;
    r[0] = f2bs(v0.x); r[1] = f2bs(v0.y); r[2] = f2bs(v0.z); r[3] = f2bs(v0.w);
    r[4] = f2bs(v1.x); r[5] = f2bs(v1.y); r[6] = f2bs(v1.z); r[7] = f2bs(v1.w);
    return r;
}

// ---------------------------------------------------------------------------
// Weight transpose + dtype-detect (fused). Each block self-detects f32-vs-bf16
// from the first 16KB of x1; block 0 publishes the flag. Then wtg[mat][d][k]
// (bf16, 64x128) from W[mat][k][d]. flag: 1 = float32 data, 0 = bf16 data.
// ---------------------------------------------------------------------------
__global__ __launch_bounds__(256) void wtrans_kernel(
    const void* __restrict__ Wa, const void* __restrict__ Wb,
    const void* __restrict__ Wc, const void* __restrict__ Wd,
    const unsigned short* __restrict__ x1probe,
    unsigned short* __restrict__ wtg, int* __restrict__ flag)
{
    __shared__ unsigned short t[DIN][DOUT + 1];
    __shared__ int cnt;
    if (threadIdx.x == 0) cnt = 0;
    __syncthreads();
    int c = 0;
#pragma unroll
    for (int i = 0; i < 16; ++i) {
        unsigned short w = x1probe[(size_t)(threadIdx.x * 16 + i) * 2];  // low half-word
        int e = (w >> 7) & 0xFF;
        c += (e >= 112 && e <= 142) ? 1 : 0;
    }
    atomicAdd(&cnt, c);
    __syncthreads();
    const int isf32 = (cnt >= 2048) ? 0 : 1;
    if (blockIdx.x == 0 && threadIdx.x == 0) *flag = isf32;

    const void* W = (blockIdx.x == 0 ? Wa : blockIdx.x == 1 ? Wb : blockIdx.x == 2 ? Wc : Wd);
    unsigned short* o = wtg + (size_t)blockIdx.x * DIN * DOUT;
    if (isf32) {
        const float* Wf = (const float*)W;
#pragma unroll 8
        for (int it = 0; it < 32; ++it) {
            int idx = threadIdx.x + 256 * it;           // 8192 elems
            t[idx >> 6][idx & 63] = (unsigned short)f2bs(Wf[idx]);
        }
    } else {
        const unsigned short* Wh = (const unsigned short*)W;
#pragma unroll 8
        for (int it = 0; it < 32; ++it) {
            int idx = threadIdx.x + 256 * it;
            t[idx >> 6][idx & 63] = Wh[idx];
        }
    }
    __syncthreads();
#pragma unroll 8
    for (int it = 0; it < 32; ++it) {
        int idx = threadIdx.x + 256 * it;
        int d = idx >> 7, k = idx & 127;
        o[idx] = t[k][d];                           // coalesced write
    }
}

// ---------------------------------------------------------------------------
// MFMA dual linear: xnh = bf16(x @ We), o[:, :64] = sigmoid(x @ Ws).
// Block tile 64 nodes x 64 d, K=128. Only the two 8KB weight tiles in LDS
// (XOR slot swizzle). A-fragments load straight from global (each x-row
// consumed exclusively by one wave). Validated rounds 4-6.
// ---------------------------------------------------------------------------
template <typename TX, typename TO>
__device__ __forceinline__ void lin_mfma_body(
    const TX* __restrict__ x,                 // [N][128] rows
    const unsigned short* __restrict__ wt2,   // 2 mats of transposed W [d][k], bf16
    bf16* __restrict__ xnh, TO* __restrict__ o,
    unsigned short* __restrict__ wt)          // LDS, 2*64*128 ushorts
{
    const int tid = threadIdx.x;
    const int nbase = blockIdx.x * NPB;

#pragma unroll
    for (int it = 0; it < 8; ++it) {
        int idx = tid + 256 * it;               // 0..2047
        int mt = idx >> 10, rem = idx & 1023;
        int r = rem >> 4, c = rem & 15;
        int4 v = *(const int4*)(wt2 + mt * 8192 + r * DIN + c * 8);
        *(int4*)(wt + mt * 8192 + r * DIN + ((c ^ (r & 15)) << 3)) = v;
    }
    __syncthreads();

    const int w = tid >> 6, lane = tid & 63;
    const int m = lane & 15, g = lane >> 4;

    int arow = nbase + w * 16 + m;
    if (arow >= N_NODES) arow = N_NODES - 1;    // tail: duplicate reads, writes guarded
    const TX* xrow = x + (size_t)arow * DIN;

    f32x4 acc[2][4] = {};
#pragma unroll
    for (int ks = 0; ks < 4; ++ks) {
        bf16x8 a = load_a8(xrow + ks * 32 + g * 8);
        int slot = ((ks * 4 + g) ^ m) << 3;     // 8-ushort slot offset
#pragma unroll
        for (int mt = 0; mt < 2; ++mt)
#pragma unroll
        for (int nc = 0; nc < 4; ++nc) {
            bf16x8 b = *(const bf16x8*)(wt + mt * 8192 + (nc * 16 + m) * DIN + slot);
            acc[mt][nc] = __builtin_amdgcn_mfma_f32_16x16x32_bf16(a, b, acc[mt][nc], 0, 0, 0);
        }
    }

#pragma unroll
    for (int nc = 0; nc < 4; ++nc) {
#pragma unroll
        for (int j = 0; j < 4; ++j) {
            int n = nbase + w * 16 + g * 4 + j;
            if (n < N_NODES) {
                int d = nc * 16 + m;
                xnh[(size_t)n * DOUT + d] = __float2bfloat16(acc[0][nc][j]);
                st(o, (size_t)n * DIN + d, sigmoidf_(acc[1][nc][j]));
            }
        }
    }
}

__global__ __launch_bounds__(256) void lin1_kernel(
    const void* __restrict__ x1, const void* __restrict__ x2,
    const unsigned short* __restrict__ wtg,
    bf16* __restrict__ xnh1, bf16* __restrict__ xnh2,
    bf16* __restrict__ h1, bf16* __restrict__ h2,
    const int* __restrict__ flag)
{
    __shared__ __align__(16) unsigned short wt[2 * DOUT * DIN];   // 32 KB
    const int g = blockIdx.y;
    const void* x   = g ? x2 : x1;
    bf16*       xnh = g ? xnh2 : xnh1;
    bf16*       h   = g ? h2 : h1;
    if (*flag) lin_mfma_body<float, bf16>((const float*)x, wtg, xnh, h, wt);
    else       lin_mfma_body<bf16,  bf16>((const bf16*)x,  wtg, xnh, h, wt);
}

__global__ __launch_bounds__(256) void lin2_kernel(
    const bf16* __restrict__ h1, const bf16* __restrict__ h2,
    const unsigned short* __restrict__ wtg,
    bf16* __restrict__ heh1, bf16* __restrict__ heh2,
    void* __restrict__ out, const int* __restrict__ flag)
{
    __shared__ __align__(16) unsigned short wt[2 * DOUT * DIN];   // 32 KB
    const int g = blockIdx.y;
    const bf16* h   = g ? h2 : h1;
    bf16*       heh = g ? heh2 : heh1;
    if (*flag) lin_mfma_body<bf16, float>(h, wtg + 2 * 8192, heh,
                                          (float*)out + (size_t)g * N_NODES * DIN, wt);
    else       lin_mfma_body<bf16, bf16>(h, wtg + 2 * 8192, heh,
                                         (bf16*)out + (size_t)g * N_NODES * DIN, wt);
}

// ---------------------------------------------------------------------------
// Pass B: aggr = (1/K) sum_k xnh[nbr[n,k]] (bf16 gather, f32 accumulate).
// SGPR-uniform indexing (round 6). Writes agh, h[:, 64:], qq/slo/shi scalars.
// ---------------------------------------------------------------------------
template <typename T>
__device__ __forceinline__ void aggr1_body(
    const int* __restrict__ nbr, const bf16* __restrict__ xnh,
    bf16* __restrict__ agh, bf16* __restrict__ h, const T* __restrict__ watt,
    float* __restrict__ qq, float* __restrict__ slo, float* __restrict__ shi)
{
    const int warp = __builtin_amdgcn_readfirstlane(threadIdx.x >> 6);
    const int lane = threadIdx.x & 63;
    const int n = blockIdx.x * 4 + warp;
    const int* __restrict__ nrow = nbr + n * K_NBR;

    float acc = 0.f;
#pragma unroll
    for (int k = 0; k < K_NBR; ++k) {
        int idx = nrow[k];                            // uniform -> s_load
        acc += b2f(xnh[(size_t)idx * DOUT + lane]);   // saddr gather, 0 addr VALU
    }
    acc *= (1.0f / K_NBR);
    bf16 av16 = __float2bfloat16(acc);
    float av = b2f(av16);
    agh[(size_t)n * DOUT + lane] = av16;
    h[(size_t)n * DIN + DOUT + lane] = __float2bfloat16(sigmoidf_(acc));

    float wl = ld(watt, lane);
    float wh = ld(watt, DOUT + lane);
    float pq = av * av;
    float pl = acc * wl;
    float ph = acc * wh;
#pragma unroll
    for (int off = 1; off < 64; off <<= 1) {
        pq += __shfl_xor(pq, off, 64);
        pl += __shfl_xor(pl, off, 64);
        ph += __shfl_xor(ph, off, 64);
    }
    if (lane == 0) { qq[n] = pq; slo[n] = pl; shi[n] = ph; }
}

__global__ __launch_bounds__(256) void aggr1_kernel(
    const int* __restrict__ nbr1, const int* __restrict__ nbr2,
    const bf16* __restrict__ xnh1, const bf16* __restrict__ xnh2,
    bf16* __restrict__ agh1, bf16* __restrict__ agh2,
    bf16* __restrict__ h1, bf16* __restrict__ h2,
    const void* __restrict__ watt,
    float* __restrict__ qq1, float* __restrict__ qq2,
    float* __restrict__ slo1, float* __restrict__ slo2,
    float* __restrict__ shi1, float* __restrict__ shi2,
    const int* __restrict__ flag)
{
    const int g = blockIdx.y;
    const int*  nbr = g ? nbr2 : nbr1;
    const bf16* xnh = g ? xnh2 : xnh1;
    bf16*       agh = g ? agh2 : agh1;
    bf16*       h   = g ? h2 : h1;
    float* qq  = g ? qq2  : qq1;
    float* slo = g ? slo2 : slo1;
    float* shi = g ? shi2 : shi1;
    if (*flag) aggr1_body<float>(nbr, xnh, agh, h, (const float*)watt, qq, slo, shi);
    else       aggr1_body<bf16>(nbr, xnh, agh, h, (const bf16*)watt,  qq, slo, shi);
}

// ---------------------------------------------------------------------------
// Pass C+E fused: self-attn + cross-attn + final weighted aggregation.
// One wave per node, zero LDS. attn math identical to rounds 4-6 (2 MFMAs,
// fragments gathered from global bf16 agh rows). The norm weights never
// leave registers: w1[k] at lane k, w2[k] at lane 16+k, broadcast per-k via
// v_readlane (VALU, no DS pipe), then aggr2's gather runs in the same wave
// with SGPR-uniform heh addressing. Removes: aggr2 launch (100k waves),
// nm write+read (12.8 MB), duplicate nbr loads. Bit-identical output.
// ---------------------------------------------------------------------------
template <typename TO>
__device__ __forceinline__ void attn_fused_body(
    const int* __restrict__ nbr1, const int* __restrict__ nbr2,
    const unsigned short* __restrict__ agh1, const unsigned short* __restrict__ agh2,
    const float* __restrict__ qq1, const float* __restrict__ qq2,
    const float* __restrict__ slo1, const float* __restrict__ slo2,
    const float* __restrict__ shi1, const float* __restrict__ shi2,
    const bf16* __restrict__ heh1, const bf16* __restrict__ heh2,
    TO* __restrict__ out)
{
    const int warp = __builtin_amdgcn_readfirstlane(threadIdx.x >> 6);
    const int lane = threadIdx.x & 63;
    const int n = blockIdx.x * 4 + warp;
    const int m = lane & 15, g = lane >> 4;

    int idxr = 0;
    if (lane < 32) idxr = ((lane < 16) ? nbr1 : nbr2)[n * K_NBR + m];

    const int i1 = __shfl(idxr, m, 64);
    const int i2 = __shfl(idxr, 16 + m, 64);

    const bf16x8* a1p = (const bf16x8*)(agh1 + (size_t)i1 * DOUT + g * 8);
    const bf16x8* a2p = (const bf16x8*)(agh2 + (size_t)i2 * DOUT + g * 8);
    bf16x8 aA = a1p[0], aB = a1p[4];   // dims 0..31, 32..63 (row i1)
    bf16x8 bA = a2p[0], bB = a2p[4];   // dims 0..31, 32..63 (row i2)

    int myidx = __shfl(idxr, lane & 31, 64);
    const float* pa = (lane < 16) ? qq1 : (lane < 32) ? qq2 : (lane < 48) ? shi1 : shi2;
    float aux = pa[(size_t)myidx];

    float si  = (lane < 16) ? slo1[n] : slo2[n];
    float sjv = __shfl(aux, 32 + (lane & 31), 64);
    float v = si + sjv;
    v = v > 0.f ? v : 0.01f * v;
    float ev = __expf(v);
    float esum = ev;
#pragma unroll
    for (int off = 1; off < 16; off <<= 1) esum += __shfl_xor(esum, off, 64);

    f32x4 acc = {};
    acc = __builtin_amdgcn_mfma_f32_16x16x32_bf16(aA, bA, acc, 0, 0, 0);
    acc = __builtin_amdgcn_mfma_f32_16x16x32_bf16(aB, bB, acc, 0, 0, 0);

    float q2c = __shfl(aux, 16 + m, 64);
    float s0, s1, s2, s3;
    {
        float q10 = __shfl(aux, g * 4 + 0, 64);
        float q11 = __shfl(aux, g * 4 + 1, 64);
        float q12 = __shfl(aux, g * 4 + 2, 64);
        float q13 = __shfl(aux, g * 4 + 3, 64);
        s0 = __expf(-sqrtf(fmaxf(q10 + q2c - 2.f * acc[0], 1e-12f)));
        s1 = __expf(-sqrtf(fmaxf(q11 + q2c - 2.f * acc[1], 1e-12f)));
        s2 = __expf(-sqrtf(fmaxf(q12 + q2c - 2.f * acc[2], 1e-12f)));
        s3 = __expf(-sqrtf(fmaxf(q13 + q2c - 2.f * acc[3], 1e-12f)));
    }

    float c = s0 + s1 + s2 + s3;
#pragma unroll
    for (int off = 1; off < 16; off <<= 1) {
        s0 += __shfl_xor(s0, off, 64);
        s1 += __shfl_xor(s1, off, 64);
        s2 += __shfl_xor(s2, off, 64);
        s3 += __shfl_xor(s3, off, 64);
    }
    float cs = c;
    cs += __shfl_xor(cs, 16, 64);
    cs += __shfl_xor(cs, 32, 64);
    float tot = cs;
#pragma unroll
    for (int off = 1; off < 16; off <<= 1) tot += __shfl_xor(tot, off, 64);
    float rt = 1.0f / tot;

    float r0 = __shfl(s0, (m >> 2) << 4, 64);
    float r1 = __shfl(s1, (m >> 2) << 4, 64);
    float r2 = __shfl(s2, (m >> 2) << 4, 64);
    float r3 = __shfl(s3, (m >> 2) << 4, 64);
    int mr = m & 3;
    float rsm = mr == 0 ? r0 : mr == 1 ? r1 : mr == 2 ? r2 : r3;

    // norm weights in-register: w1[k] at lane k (g==0), w2[k] at lane 16+k (g==1).
    // Same expression previously stored to nm -> bit-identical weights.
    float wv = (g == 0) ? (rsm * rt * ev / esum)
             : (g == 1) ? (cs  * rt * ev / esum) : 0.f;

    // ---- fused final aggregation (was aggr2_kernel) ----
    const int* __restrict__ nrow1 = nbr1 + n * K_NBR;   // uniform -> s_load
    const int* __restrict__ nrow2 = nbr2 + n * K_NBR;
    float acc1 = 0.f, acc2 = 0.f;
#pragma unroll
    for (int k = 0; k < K_NBR; ++k) {
        float w1k = readlane_f(wv, k);
        float w2k = readlane_f(wv, 16 + k);
        int j1 = nrow1[k];
        int j2 = nrow2[k];
        acc1 += w1k * b2f(heh1[(size_t)j1 * DOUT + lane]);   // saddr gather
        acc2 += w2k * b2f(heh2[(size_t)j2 * DOUT + lane]);
    }
    st(out, (size_t)n * DIN + DOUT + lane, sigmoidf_(acc1));                       // graph 1
    st(out, ((size_t)N_NODES + n) * DIN + DOUT + lane, sigmoidf_(acc2));           // graph 2
}

__global__ __launch_bounds__(256) void attn_kernel(
    const int* __restrict__ nbr1, const int* __restrict__ nbr2,
    const unsigned short* __restrict__ agh1, const unsigned short* __restrict__ agh2,
    const float* __restrict__ qq1, const float* __restrict__ qq2,
    const float* __restrict__ slo1, const float* __restrict__ slo2,
    const float* __restrict__ shi1, const float* __restrict__ shi2,
    const bf16* __restrict__ heh1, const bf16* __restrict__ heh2,
    void* __restrict__ out, const int* __restrict__ flag)
{
    if (*flag) attn_fused_body<float>(nbr1, nbr2, agh1, agh2, qq1, qq2, slo1, slo2,
                                      shi1, shi2, heh1, heh2, (float*)out);
    else       attn_fused_body<bf16>(nbr1, nbr2, agh1, agh2, qq1, qq2, slo1, slo2,
                                     shi1, shi2, heh1, heh2, (bf16*)out);
}

// ---------------------------------------------------------------------------
extern "C" void kernel_launch(void* const* d_in, const int* in_sizes, int n_in,
                              void* d_out, int out_size, void* d_ws, size_t ws_size,
                              hipStream_t stream)
{
    const void* x1   = d_in[0];
    const void* x2   = d_in[1];
    const int*  nbr1 = (const int*)d_in[2];
    const int*  nbr2 = (const int*)d_in[3];
    const void* We1  = d_in[4];
    const void* Ws1  = d_in[5];
    const void* We2  = d_in[6];
    const void* Ws2  = d_in[7];
    const void* watt = d_in[8];

    char* ws = (char*)d_ws;
    const size_t SZH  = (size_t)N_NODES * DOUT * sizeof(bf16);   // 6.4 MB
    const size_t HSZ  = (size_t)N_NODES * DIN * sizeof(bf16);    // 12.8 MB
    const size_t NSZ  = (size_t)N_NODES * sizeof(float);         //  0.2 MB
    bf16* xnh1 = (bf16*)(ws + 0 * SZH);   // later reused as heh1
    bf16* xnh2 = (bf16*)(ws + 1 * SZH);   // later reused as heh2
    bf16* agh1 = (bf16*)(ws + 2 * SZH);
    bf16* agh2 = (bf16*)(ws + 3 * SZH);
    bf16* h1   = (bf16*)(ws + 4 * SZH);
    bf16* h2   = (bf16*)(ws + 4 * SZH + HSZ);
    char* p    =         ws + 4 * SZH + 2 * HSZ;
    int*  flag = (int*)  (p);
    char* aux  =          p + 4096;
    float* qq1  = (float*)(aux + 0 * NSZ);
    float* qq2  = (float*)(aux + 1 * NSZ);
    float* slo1 = (float*)(aux + 2 * NSZ);
    float* slo2 = (float*)(aux + 3 * NSZ);
    float* shi1 = (float*)(aux + 4 * NSZ);
    float* shi2 = (float*)(aux + 5 * NSZ);
    unsigned short* wtg = (unsigned short*)(aux + 6 * NSZ);  // 4 x 16KB transposed bf16 W

    dim3 b(256);
    dim3 g4(N_NODES / 4, 2);                       // aggr1: 1 wave/node
    dim3 gl((N_NODES + NPB - 1) / NPB, 2);         // linear kernels: 64 nodes/block
    dim3 ga(N_NODES / 4);                          // fused attn: 4 node-waves/block

    wtrans_kernel<<<dim3(4), b, 0, stream>>>(We1, Ws1, We2, Ws2,
                                             (const unsigned short*)x1, wtg, flag);
    lin1_kernel <<<gl, b, 0, stream>>>(x1, x2, wtg, xnh1, xnh2, h1, h2, flag);
    aggr1_kernel<<<g4, b, 0, stream>>>(nbr1, nbr2, xnh1, xnh2, agh1, agh2, h1, h2,
                                       watt, qq1, qq2, slo1, slo2, shi1, shi2, flag);
    lin2_kernel <<<gl, b, 0, stream>>>(h1, h2, wtg, xnh1, xnh2, d_out, flag);
    attn_kernel <<<ga, b, 0, stream>>>(nbr1, nbr2, (const unsigned short*)agh1,
                                       (const unsigned short*)agh2, qq1, qq2,
                                       slo1, slo2, shi1, shi2, xnh1, xnh2,
                                       d_out, flag);
}

// Round 8
// 230.328 us; speedup vs baseline: 3.2295x; 1.0011x over previous
//
#include <hip/hip_runtime.h>
#include <hip/hip_bf16.h>

#define N_NODES 50000
#define K_NBR   16
#define DIN     128
#define DOUT    64
#define NPB     64   // nodes per block in the linear kernels

typedef __hip_bfloat16 bf16;
typedef __attribute__((ext_vector_type(8))) short bf16x8;
typedef __attribute__((ext_vector_type(4))) float f32x4;

__device__ __forceinline__ float b2f(bf16 v) { return __bfloat162float(v); }
__device__ __forceinline__ float us2f(unsigned short u) {        // bf16 bits -> f32 (exact)
    return __uint_as_float(((unsigned)u) << 16);
}
__device__ __forceinline__ float sigmoidf_(float x) { return 1.0f / (1.0f + __expf(-x)); }
__device__ __forceinline__ short f2bs(float f) {
    bf16 b = __float2bfloat16(f);
    return *reinterpret_cast<short*>(&b);
}
// lane-constant broadcast without touching the DS pipe
__device__ __forceinline__ float readlane_f(float v, int lane) {
    return __uint_as_float(__builtin_amdgcn_readlane(__float_as_uint(v), lane));
}

template <typename T> __device__ __forceinline__ float ld(const T* p, size_t i);
template <> __device__ __forceinline__ float ld<float>(const float* p, size_t i) { return p[i]; }
template <> __device__ __forceinline__ float ld<bf16>(const bf16* p, size_t i)   { return b2f(p[i]); }

template <typename T> __device__ __forceinline__ void st(T* p, size_t i, float v);
template <> __device__ __forceinline__ void st<float>(float* p, size_t i, float v) { p[i] = v; }
template <> __device__ __forceinline__ void st<bf16>(bf16* p, size_t i, float v)   { p[i] = __float2bfloat16(v); }

// A-fragment loaders: 8 k-contiguous bf16 values from a global row.
__device__ __forceinline__ bf16x8 load_a8(const bf16* p) { return *(const bf16x8*)p; }
__device__ __forceinline__ bf16x8 load_a8(const float* p) {
    float4 v0 = *(const float4*)p;
    float4 v1 = *(const float4*)(p + 4);
    bf16x8 r;
    r[0] = f2bs(v0.x); r[1] = f2bs(v0.y); r[2] = f2bs(v0.z); r[3] = f2bs(v0.w);
    r[4] = f2bs(v1.x); r[5] = f2bs(v1.y); r[6] = f2bs(v1.z); r[7] = f2bs(v1.w);
    return r;
}

// ---------------------------------------------------------------------------
// Weight transpose + dtype-detect (fused). flag: 1 = float32, 0 = bf16.
// ---------------------------------------------------------------------------
__global__ __launch_bounds__(256) void wtrans_kernel(
    const void* __restrict__ Wa, const void* __restrict__ Wb,
    const void* __restrict__ Wc, const void* __restrict__ Wd,
    const unsigned short* __restrict__ x1probe,
    unsigned short* __restrict__ wtg, int* __restrict__ flag)
{
    __shared__ unsigned short t[DIN][DOUT + 1];
    __shared__ int cnt;
    if (threadIdx.x == 0) cnt = 0;
    __syncthreads();
    int c = 0;
#pragma unroll
    for (int i = 0; i < 16; ++i) {
        unsigned short w = x1probe[(size_t)(threadIdx.x * 16 + i) * 2];  // low half-word
        int e = (w >> 7) & 0xFF;
        c += (e >= 112 && e <= 142) ? 1 : 0;
    }
    atomicAdd(&cnt, c);
    __syncthreads();
    const int isf32 = (cnt >= 2048) ? 0 : 1;
    if (blockIdx.x == 0 && threadIdx.x == 0) *flag = isf32;

    const void* W = (blockIdx.x == 0 ? Wa : blockIdx.x == 1 ? Wb : blockIdx.x == 2 ? Wc : Wd);
    unsigned short* o = wtg + (size_t)blockIdx.x * DIN * DOUT;
    if (isf32) {
        const float* Wf = (const float*)W;
#pragma unroll 8
        for (int it = 0; it < 32; ++it) {
            int idx = threadIdx.x + 256 * it;           // 8192 elems
            t[idx >> 6][idx & 63] = (unsigned short)f2bs(Wf[idx]);
        }
    } else {
        const unsigned short* Wh = (const unsigned short*)W;
#pragma unroll 8
        for (int it = 0; it < 32; ++it) {
            int idx = threadIdx.x + 256 * it;
            t[idx >> 6][idx & 63] = Wh[idx];
        }
    }
    __syncthreads();
#pragma unroll 8
    for (int it = 0; it < 32; ++it) {
        int idx = threadIdx.x + 256 * it;
        int d = idx >> 7, k = idx & 127;
        o[idx] = t[k][d];                           // coalesced write
    }
}

// ---------------------------------------------------------------------------
// MFMA dual linear: xnh = bf16(x @ We), o[:, :64] = sigmoid(x @ Ws).
// Validated rounds 4-7.
// ---------------------------------------------------------------------------
template <typename TX, typename TO>
__device__ __forceinline__ void lin_mfma_body(
    const TX* __restrict__ x,                 // [N][128] rows
    const unsigned short* __restrict__ wt2,   // 2 mats of transposed W [d][k], bf16
    bf16* __restrict__ xnh, TO* __restrict__ o,
    unsigned short* __restrict__ wt)          // LDS, 2*64*128 ushorts
{
    const int tid = threadIdx.x;
    const int nbase = blockIdx.x * NPB;

#pragma unroll
    for (int it = 0; it < 8; ++it) {
        int idx = tid + 256 * it;               // 0..2047
        int mt = idx >> 10, rem = idx & 1023;
        int r = rem >> 4, c = rem & 15;
        int4 v = *(const int4*)(wt2 + mt * 8192 + r * DIN + c * 8);
        *(int4*)(wt + mt * 8192 + r * DIN + ((c ^ (r & 15)) << 3)) = v;
    }
    __syncthreads();

    const int w = tid >> 6, lane = tid & 63;
    const int m = lane & 15, g = lane >> 4;

    int arow = nbase + w * 16 + m;
    if (arow >= N_NODES) arow = N_NODES - 1;    // tail: duplicate reads, writes guarded
    const TX* xrow = x + (size_t)arow * DIN;

    f32x4 acc[2][4] = {};
#pragma unroll
    for (int ks = 0; ks < 4; ++ks) {
        bf16x8 a = load_a8(xrow + ks * 32 + g * 8);
        int slot = ((ks * 4 + g) ^ m) << 3;     // 8-ushort slot offset
#pragma unroll
        for (int mt = 0; mt < 2; ++mt)
#pragma unroll
        for (int nc = 0; nc < 4; ++nc) {
            bf16x8 b = *(const bf16x8*)(wt + mt * 8192 + (nc * 16 + m) * DIN + slot);
            acc[mt][nc] = __builtin_amdgcn_mfma_f32_16x16x32_bf16(a, b, acc[mt][nc], 0, 0, 0);
        }
    }

#pragma unroll
    for (int nc = 0; nc < 4; ++nc) {
#pragma unroll
        for (int j = 0; j < 4; ++j) {
            int n = nbase + w * 16 + g * 4 + j;
            if (n < N_NODES) {
                int d = nc * 16 + m;
                xnh[(size_t)n * DOUT + d] = __float2bfloat16(acc[0][nc][j]);
                st(o, (size_t)n * DIN + d, sigmoidf_(acc[1][nc][j]));
            }
        }
    }
}

__global__ __launch_bounds__(256) void lin1_kernel(
    const void* __restrict__ x1, const void* __restrict__ x2,
    const unsigned short* __restrict__ wtg,
    bf16* __restrict__ xnh1, bf16* __restrict__ xnh2,
    bf16* __restrict__ h1, bf16* __restrict__ h2,
    const int* __restrict__ flag)
{
    __shared__ __align__(16) unsigned short wt[2 * DOUT * DIN];   // 32 KB
    const int g = blockIdx.y;
    const void* x   = g ? x2 : x1;
    bf16*       xnh = g ? xnh2 : xnh1;
    bf16*       h   = g ? h2 : h1;
    if (*flag) lin_mfma_body<float, bf16>((const float*)x, wtg, xnh, h, wt);
    else       lin_mfma_body<bf16,  bf16>((const bf16*)x,  wtg, xnh, h, wt);
}

__global__ __launch_bounds__(256) void lin2_kernel(
    const bf16* __restrict__ h1, const bf16* __restrict__ h2,
    const unsigned short* __restrict__ wtg,
    bf16* __restrict__ heh1, bf16* __restrict__ heh2,
    void* __restrict__ out, const int* __restrict__ flag)
{
    __shared__ __align__(16) unsigned short wt[2 * DOUT * DIN];   // 32 KB
    const int g = blockIdx.y;
    const bf16* h   = g ? h2 : h1;
    bf16*       heh = g ? heh2 : heh1;
    if (*flag) lin_mfma_body<bf16, float>(h, wtg + 2 * 8192, heh,
                                          (float*)out + (size_t)g * N_NODES * DIN, wt);
    else       lin_mfma_body<bf16, bf16>(h, wtg + 2 * 8192, heh,
                                         (bf16*)out + (size_t)g * N_NODES * DIN, wt);
}

// ---------------------------------------------------------------------------
// Pass B: aggr = (1/K) sum_k xnh[nbr[n,k]]. SGPR-uniform indexing (round 6)
// + explicit gather prefetch: all 16 per-lane payloads issued before the
// reduce so the 16 loads pipeline instead of serializing (VGPR was 36 ->
// compiler had serialized them).
// ---------------------------------------------------------------------------
template <typename T>
__device__ __forceinline__ void aggr1_body(
    const int* __restrict__ nbr, const bf16* __restrict__ xnh,
    bf16* __restrict__ agh, bf16* __restrict__ h, const T* __restrict__ watt,
    float* __restrict__ qq, float* __restrict__ slo, float* __restrict__ shi)
{
    const int warp = __builtin_amdgcn_readfirstlane(threadIdx.x >> 6);
    const int lane = threadIdx.x & 63;
    const int n = blockIdx.x * 4 + warp;
    const int* __restrict__ nrow = nbr + n * K_NBR;
    const unsigned short* __restrict__ xu = (const unsigned short*)xnh;

    unsigned short xv[K_NBR];
#pragma unroll
    for (int k = 0; k < K_NBR; ++k)
        xv[k] = xu[(size_t)nrow[k] * DOUT + lane];    // uniform saddr, all in flight

    float acc = 0.f;
#pragma unroll
    for (int k = 0; k < K_NBR; ++k) acc += us2f(xv[k]);
    acc *= (1.0f / K_NBR);
    bf16 av16 = __float2bfloat16(acc);
    float av = b2f(av16);
    agh[(size_t)n * DOUT + lane] = av16;
    h[(size_t)n * DIN + DOUT + lane] = __float2bfloat16(sigmoidf_(acc));

    float wl = ld(watt, lane);
    float wh = ld(watt, DOUT + lane);
    float pq = av * av;
    float pl = acc * wl;
    float ph = acc * wh;
#pragma unroll
    for (int off = 1; off < 64; off <<= 1) {
        pq += __shfl_xor(pq, off, 64);
        pl += __shfl_xor(pl, off, 64);
        ph += __shfl_xor(ph, off, 64);
    }
    if (lane == 0) { qq[n] = pq; slo[n] = pl; shi[n] = ph; }
}

__global__ __launch_bounds__(256) void aggr1_kernel(
    const int* __restrict__ nbr1, const int* __restrict__ nbr2,
    const bf16* __restrict__ xnh1, const bf16* __restrict__ xnh2,
    bf16* __restrict__ agh1, bf16* __restrict__ agh2,
    bf16* __restrict__ h1, bf16* __restrict__ h2,
    const void* __restrict__ watt,
    float* __restrict__ qq1, float* __restrict__ qq2,
    float* __restrict__ slo1, float* __restrict__ slo2,
    float* __restrict__ shi1, float* __restrict__ shi2,
    const int* __restrict__ flag)
{
    const int g = blockIdx.y;
    const int*  nbr = g ? nbr2 : nbr1;
    const bf16* xnh = g ? xnh2 : xnh1;
    bf16*       agh = g ? agh2 : agh1;
    bf16*       h   = g ? h2 : h1;
    float* qq  = g ? qq2  : qq1;
    float* slo = g ? slo2 : slo1;
    float* shi = g ? shi2 : shi1;
    if (*flag) aggr1_body<float>(nbr, xnh, agh, h, (const float*)watt, qq, slo, shi);
    else       aggr1_body<bf16>(nbr, xnh, agh, h, (const bf16*)watt,  qq, slo, shi);
}

// ---------------------------------------------------------------------------
// Pass C+E fused: self-attn + cross-attn + final weighted aggregation.
// One wave per node, zero LDS. ROUND 8: the 32 heh payload gathers depend
// only on the s_loaded nbr rows -> issue them ALL at the top of the kernel
// (16 VGPRs of payload); the attn math (MFMAs, exp/sqrt, butterflies) hides
// their latency; the weighted sum at the end consumes registers. Round 7 had
// VGPR=24 -> compiler serialized these loads, exposing the full gather
// latency AFTER the attn math (61.6us = VALU-time + memory-time).
// ---------------------------------------------------------------------------
template <typename TO>
__device__ __forceinline__ void attn_fused_body(
    const int* __restrict__ nbr1, const int* __restrict__ nbr2,
    const unsigned short* __restrict__ agh1, const unsigned short* __restrict__ agh2,
    const float* __restrict__ qq1, const float* __restrict__ qq2,
    const float* __restrict__ slo1, const float* __restrict__ slo2,
    const float* __restrict__ shi1, const float* __restrict__ shi2,
    const bf16* __restrict__ heh1, const bf16* __restrict__ heh2,
    TO* __restrict__ out)
{
    const int warp = __builtin_amdgcn_readfirstlane(threadIdx.x >> 6);
    const int lane = threadIdx.x & 63;
    const int n = blockIdx.x * 4 + warp;
    const int m = lane & 15, g = lane >> 4;

    // ---- phase 0: issue ALL independent gathers up front ----
    const int* __restrict__ nrow1 = nbr1 + n * K_NBR;   // uniform -> s_load
    const int* __restrict__ nrow2 = nbr2 + n * K_NBR;
    const unsigned short* __restrict__ hu1 = (const unsigned short*)heh1;
    const unsigned short* __restrict__ hu2 = (const unsigned short*)heh2;

    unsigned short hv1[K_NBR], hv2[K_NBR];
#pragma unroll
    for (int k = 0; k < K_NBR; ++k) {
        hv1[k] = hu1[(size_t)nrow1[k] * DOUT + lane];   // saddr gathers, all in flight
        hv2[k] = hu2[(size_t)nrow2[k] * DOUT + lane];
    }

    int idxr = 0;
    if (lane < 32) idxr = ((lane < 16) ? nbr1 : nbr2)[n * K_NBR + m];

    const int i1 = __shfl(idxr, m, 64);
    const int i2 = __shfl(idxr, 16 + m, 64);

    const bf16x8* a1p = (const bf16x8*)(agh1 + (size_t)i1 * DOUT + g * 8);
    const bf16x8* a2p = (const bf16x8*)(agh2 + (size_t)i2 * DOUT + g * 8);
    bf16x8 aA = a1p[0], aB = a1p[4];   // dims 0..31, 32..63 (row i1)
    bf16x8 bA = a2p[0], bB = a2p[4];   // dims 0..31, 32..63 (row i2)

    int myidx = __shfl(idxr, lane & 31, 64);
    const float* pa = (lane < 16) ? qq1 : (lane < 32) ? qq2 : (lane < 48) ? shi1 : shi2;
    float aux = pa[(size_t)myidx];

    // ---- phase 1: attention math (hides phase-0 latency) ----
    float si  = (lane < 16) ? slo1[n] : slo2[n];
    float sjv = __shfl(aux, 32 + (lane & 31), 64);
    float v = si + sjv;
    v = v > 0.f ? v : 0.01f * v;
    float ev = __expf(v);
    float esum = ev;
#pragma unroll
    for (int off = 1; off < 16; off <<= 1) esum += __shfl_xor(esum, off, 64);

    f32x4 acc = {};
    acc = __builtin_amdgcn_mfma_f32_16x16x32_bf16(aA, bA, acc, 0, 0, 0);
    acc = __builtin_amdgcn_mfma_f32_16x16x32_bf16(aB, bB, acc, 0, 0, 0);

    float q2c = __shfl(aux, 16 + m, 64);
    float s0, s1, s2, s3;
    {
        float q10 = __shfl(aux, g * 4 + 0, 64);
        float q11 = __shfl(aux, g * 4 + 1, 64);
        float q12 = __shfl(aux, g * 4 + 2, 64);
        float q13 = __shfl(aux, g * 4 + 3, 64);
        s0 = __expf(-sqrtf(fmaxf(q10 + q2c - 2.f * acc[0], 1e-12f)));
        s1 = __expf(-sqrtf(fmaxf(q11 + q2c - 2.f * acc[1], 1e-12f)));
        s2 = __expf(-sqrtf(fmaxf(q12 + q2c - 2.f * acc[2], 1e-12f)));
        s3 = __expf(-sqrtf(fmaxf(q13 + q2c - 2.f * acc[3], 1e-12f)));
    }

    float c = s0 + s1 + s2 + s3;
#pragma unroll
    for (int off = 1; off < 16; off <<= 1) {
        s0 += __shfl_xor(s0, off, 64);
        s1 += __shfl_xor(s1, off, 64);
        s2 += __shfl_xor(s2, off, 64);
        s3 += __shfl_xor(s3, off, 64);
    }
    float cs = c;
    cs += __shfl_xor(cs, 16, 64);
    cs += __shfl_xor(cs, 32, 64);
    float tot = cs;
#pragma unroll
    for (int off = 1; off < 16; off <<= 1) tot += __shfl_xor(tot, off, 64);
    float rt = 1.0f / tot;

    float r0 = __shfl(s0, (m >> 2) << 4, 64);
    float r1 = __shfl(s1, (m >> 2) << 4, 64);
    float r2 = __shfl(s2, (m >> 2) << 4, 64);
    float r3 = __shfl(s3, (m >> 2) << 4, 64);
    int mr = m & 3;
    float rsm = mr == 0 ? r0 : mr == 1 ? r1 : mr == 2 ? r2 : r3;

    // norm weights in-register: w1[k] at lane k (g==0), w2[k] at lane 16+k (g==1)
    float wv = (g == 0) ? (rsm * rt * ev / esum)
             : (g == 1) ? (cs  * rt * ev / esum) : 0.f;

    // ---- phase 2: weighted sum over prefetched registers ----
    float acc1 = 0.f, acc2 = 0.f;
#pragma unroll
    for (int k = 0; k < K_NBR; ++k) {
        acc1 += readlane_f(wv, k)      * us2f(hv1[k]);
        acc2 += readlane_f(wv, 16 + k) * us2f(hv2[k]);
    }
    st(out, (size_t)n * DIN + DOUT + lane, sigmoidf_(acc1));                 // graph 1
    st(out, ((size_t)N_NODES + n) * DIN + DOUT + lane, sigmoidf_(acc2));     // graph 2
}

__global__ __launch_bounds__(256) void attn_kernel(
    const int* __restrict__ nbr1, const int* __restrict__ nbr2,
    const unsigned short* __restrict__ agh1, const unsigned short* __restrict__ agh2,
    const float* __restrict__ qq1, const float* __restrict__ qq2,
    const float* __restrict__ slo1, const float* __restrict__ slo2,
    const float* __restrict__ shi1, const float* __restrict__ shi2,
    const bf16* __restrict__ heh1, const bf16* __restrict__ heh2,
    void* __restrict__ out, const int* __restrict__ flag)
{
    if (*flag) attn_fused_body<float>(nbr1, nbr2, agh1, agh2, qq1, qq2, slo1, slo2,
                                      shi1, shi2, heh1, heh2, (float*)out);
    else       attn_fused_body<bf16>(nbr1, nbr2, agh1, agh2, qq1, qq2, slo1, slo2,
                                     shi1, shi2, heh1, heh2, (bf16*)out);
}

// ---------------------------------------------------------------------------
extern "C" void kernel_launch(void* const* d_in, const int* in_sizes, int n_in,
                              void* d_out, int out_size, void* d_ws, size_t ws_size,
                              hipStream_t stream)
{
    const void* x1   = d_in[0];
    const void* x2   = d_in[1];
    const int*  nbr1 = (const int*)d_in[2];
    const int*  nbr2 = (const int*)d_in[3];
    const void* We1  = d_in[4];
    const void* Ws1  = d_in[5];
    const void* We2  = d_in[6];
    const void* Ws2  = d_in[7];
    const void* watt = d_in[8];

    char* ws = (char*)d_ws;
    const size_t SZH  = (size_t)N_NODES * DOUT * sizeof(bf16);   // 6.4 MB
    const size_t HSZ  = (size_t)N_NODES * DIN * sizeof(bf16);    // 12.8 MB
    const size_t NSZ  = (size_t)N_NODES * sizeof(float);         //  0.2 MB
    bf16* xnh1 = (bf16*)(ws + 0 * SZH);   // later reused as heh1
    bf16* xnh2 = (bf16*)(ws + 1 * SZH);   // later reused as heh2
    bf16* agh1 = (bf16*)(ws + 2 * SZH);
    bf16* agh2 = (bf16*)(ws + 3 * SZH);
    bf16* h1   = (bf16*)(ws + 4 * SZH);
    bf16* h2   = (bf16*)(ws + 4 * SZH + HSZ);
    char* p    =         ws + 4 * SZH + 2 * HSZ;
    int*  flag = (int*)  (p);
    char* aux  =          p + 4096;
    float* qq1  = (float*)(aux + 0 * NSZ);
    float* qq2  = (float*)(aux + 1 * NSZ);
    float* slo1 = (float*)(aux + 2 * NSZ);
    float* slo2 = (float*)(aux + 3 * NSZ);
    float* shi1 = (float*)(aux + 4 * NSZ);
    float* shi2 = (float*)(aux + 5 * NSZ);
    unsigned short* wtg = (unsigned short*)(aux + 6 * NSZ);  // 4 x 16KB transposed bf16 W

    dim3 b(256);
    dim3 g4(N_NODES / 4, 2);                       // aggr1: 1 wave/node
    dim3 gl((N_NODES + NPB - 1) / NPB, 2);         // linear kernels: 64 nodes/block
    dim3 ga(N_NODES / 4);                          // fused attn: 4 node-waves/block

    wtrans_kernel<<<dim3(4), b, 0, stream>>>(We1, Ws1, We2, Ws2,
                                             (const unsigned short*)x1, wtg, flag);
    lin1_kernel <<<gl, b, 0, stream>>>(x1, x2, wtg, xnh1, xnh2, h1, h2, flag);
    aggr1_kernel<<<g4, b, 0, stream>>>(nbr1, nbr2, xnh1, xnh2, agh1, agh2, h1, h2,
                                       watt, qq1, qq2, slo1, slo2, shi1, shi2, flag);
    lin2_kernel <<<gl, b, 0, stream>>>(h1, h2, wtg, xnh1, xnh2, d_out, flag);
    attn_kernel <<<ga, b, 0, stream>>>(nbr1, nbr2, (const unsigned short*)agh1,
                                       (const unsigned short*)agh2, qq1, qq2,
                                       slo1, slo2, shi1, shi2, xnh1, xnh2,
                                       d_out, flag);
}